// Round 1
// baseline (2521.775 us; speedup 1.0000x reference)
//
#include <hip/hip_runtime.h>
#include <math.h>

#define B_ 32
#define N_ 576
#define C_ 1024
#define INNER_ 256
#define H_ 4
#define HD_ 64
#define M_ (B_*N_)           // 18432
#define ALPHA_ 5.0f
#define EPS_ 1e-5f

// ---------------------------------------------------------------------------
// Kernel 1: per-row LayerNorm stats (mean, rstd). One wave per row.
// ---------------------------------------------------------------------------
__global__ void ln_stats_kernel(const float* __restrict__ X,
                                float* __restrict__ mu, float* __restrict__ rs) {
    int row = blockIdx.x * 4 + (threadIdx.x >> 6);
    int lane = threadIdx.x & 63;
    const float* xp = X + (size_t)row * C_;
    float s = 0.f, s2 = 0.f;
    #pragma unroll
    for (int i = 0; i < C_/64; ++i) {
        float v = xp[lane + i*64];
        s += v; s2 += v*v;
    }
    #pragma unroll
    for (int m = 32; m; m >>= 1) {
        s  += __shfl_xor(s,  m, 64);
        s2 += __shfl_xor(s2, m, 64);
    }
    if (lane == 0) {
        float mean = s * (1.f/C_);
        float var  = s2 * (1.f/C_) - mean*mean;
        mu[row] = mean;
        rs[row] = rsqrtf(var + EPS_);
    }
}

// ---------------------------------------------------------------------------
// Kernel 2: Out[m][o] = sum_k LN(X)[m][k] * W[o][k] + bias[o]
// LN applied on the fly while staging the A tile.
// 64x64 tile, BK=16, 256 threads, 4x4 per thread.
// ---------------------------------------------------------------------------
template<int KDIM>
__global__ void ln_gemm_kernel(const float* __restrict__ X, const float* __restrict__ mu,
                               const float* __restrict__ rs, const float* __restrict__ lw,
                               const float* __restrict__ lb, const float* __restrict__ W,
                               const float* __restrict__ bias, float* __restrict__ Out,
                               int Nout) {
    __shared__ float As[64][17];
    __shared__ float Bs[16][65];
    int tid = threadIdx.x;
    int tx = tid & 15, ty = tid >> 4;
    int row0 = blockIdx.y * 64, col0 = blockIdx.x * 64;
    float acc[4][4] = {};
    for (int k0 = 0; k0 < KDIM; k0 += 16) {
        #pragma unroll
        for (int i = 0; i < 4; ++i) {
            int lin = tid + i*256;
            int r = lin >> 4, kk = lin & 15;
            int grow = row0 + r, gk = k0 + kk;
            float v = X[(size_t)grow * KDIM + gk];
            As[r][kk] = (v - mu[grow]) * rs[grow] * lw[gk] + lb[gk];
            Bs[kk][r] = W[(size_t)(col0 + r) * KDIM + gk];
        }
        __syncthreads();
        #pragma unroll
        for (int kk = 0; kk < 16; ++kk) {
            float a[4], b[4];
            #pragma unroll
            for (int i = 0; i < 4; ++i) a[i] = As[ty*4+i][kk];
            #pragma unroll
            for (int j = 0; j < 4; ++j) b[j] = Bs[kk][tx*4+j];
            #pragma unroll
            for (int i = 0; i < 4; ++i)
                #pragma unroll
                for (int j = 0; j < 4; ++j)
                    acc[i][j] += a[i]*b[j];
        }
        __syncthreads();
    }
    #pragma unroll
    for (int i = 0; i < 4; ++i) {
        int r = row0 + ty*4 + i;
        #pragma unroll
        for (int j = 0; j < 4; ++j) {
            int c = col0 + tx*4 + j;
            Out[(size_t)r * Nout + c] = acc[i][j] + bias[c];
        }
    }
}

// ---------------------------------------------------------------------------
// Kernel 3: attention for one (b,h) and 16 query rows per block.
// scores in LDS -> softmax -> write attn to d_out -> ctx = P @ V.
// ---------------------------------------------------------------------------
__global__ void attn_kernel(const float* __restrict__ Qb, const float* __restrict__ Kb,
                            const float* __restrict__ Vb, const float* __restrict__ mask,
                            float* __restrict__ attn_out, float* __restrict__ ctx) {
    __shared__ float Qs[16][HD_];
    __shared__ float Ks[16][HD_+1];
    __shared__ float S[16][N_];
    int tid = threadIdx.x;
    int bh = blockIdx.y;
    int b = bh >> 2, h = bh & 3;
    int q0 = blockIdx.x * 16;

    // load 16 Q rows
    #pragma unroll
    for (int i = 0; i < 4; ++i) {
        int lin = tid + i*256;
        int r = lin >> 6, d = lin & 63;
        Qs[r][d] = Qb[(size_t)(b*N_ + q0 + r) * INNER_ + h*HD_ + d];
    }
    __syncthreads();

    int rr = tid >> 4, jl = tid & 15;
    // scores
    for (int j0 = 0; j0 < N_; j0 += 16) {
        #pragma unroll
        for (int i = 0; i < 4; ++i) {
            int lin = tid + i*256;
            int r = lin >> 6, d = lin & 63;
            Ks[r][d] = Kb[(size_t)(b*N_ + j0 + r) * INNER_ + h*HD_ + d];
        }
        __syncthreads();
        float s = 0.f;
        #pragma unroll
        for (int d = 0; d < HD_; ++d) s += Qs[rr][d]*Ks[jl][d];
        S[rr][j0 + jl] = s * 0.125f + ALPHA_ * mask[b*N_ + j0 + jl];
        __syncthreads();
    }

    // softmax: 16 threads per row
    {
        int r = tid >> 4, l = tid & 15;
        float m = -1e30f;
        for (int t = l; t < N_; t += 16) m = fmaxf(m, S[r][t]);
        #pragma unroll
        for (int msk = 8; msk; msk >>= 1) m = fmaxf(m, __shfl_xor(m, msk, 16));
        float sum = 0.f;
        for (int t = l; t < N_; t += 16) { float e = expf(S[r][t] - m); S[r][t] = e; sum += e; }
        #pragma unroll
        for (int msk = 8; msk; msk >>= 1) sum += __shfl_xor(sum, msk, 16);
        float inv = 1.f / sum;
        for (int t = l; t < N_; t += 16) S[r][t] *= inv;
    }
    __syncthreads();

    // write attn rows (coalesced)
    float* ap = attn_out + ((size_t)bh * N_ + q0) * N_;
    for (int idx = tid; idx < 16*N_; idx += 256) {
        int r = idx / N_;
        int t = idx - r*N_;
        ap[(size_t)r*N_ + t] = S[r][t];
    }

    // ctx = P @ V
    float acc[4] = {0.f,0.f,0.f,0.f};
    int dl = tid & 15;
    for (int j0 = 0; j0 < N_; j0 += 16) {
        __syncthreads();
        #pragma unroll
        for (int i = 0; i < 4; ++i) {
            int lin = tid + i*256;
            int r = lin >> 6, d = lin & 63;
            Ks[r][d] = Vb[(size_t)(b*N_ + j0 + r) * INNER_ + h*HD_ + d];
        }
        __syncthreads();
        #pragma unroll
        for (int jj = 0; jj < 16; ++jj) {
            float p = S[rr][j0+jj];
            #pragma unroll
            for (int i = 0; i < 4; ++i)
                acc[i] += p * Ks[jj][dl + 16*i];
        }
    }
    #pragma unroll
    for (int i = 0; i < 4; ++i)
        ctx[(size_t)(b*N_ + q0 + rr) * INNER_ + h*HD_ + dl + 16*i] = acc[i];
}

// ---------------------------------------------------------------------------
// Kernel 4: enhanced = X + sigmoid(X@Wg^T + bg) * (ctx@Wo^T + bo)
// Two K-loops (256 and 1024) into two accumulators, fused epilogue.
// ---------------------------------------------------------------------------
__global__ void final_kernel(const float* __restrict__ ctx, const float* __restrict__ Wo,
                             const float* __restrict__ bo, const float* __restrict__ X,
                             const float* __restrict__ Wg, const float* __restrict__ bg,
                             float* __restrict__ outp) {
    __shared__ float As[64][17];
    __shared__ float Bs[16][65];
    int tid = threadIdx.x;
    int tx = tid & 15, ty = tid >> 4;
    int row0 = blockIdx.y * 64, col0 = blockIdx.x * 64;
    float acc_o[4][4] = {};
    float acc_g[4][4] = {};

    // ctx @ Wo^T (K = 256)
    for (int k0 = 0; k0 < INNER_; k0 += 16) {
        #pragma unroll
        for (int i = 0; i < 4; ++i) {
            int lin = tid + i*256;
            int r = lin >> 4, kk = lin & 15;
            As[r][kk] = ctx[(size_t)(row0 + r)*INNER_ + k0 + kk];
            Bs[kk][r] = Wo[(size_t)(col0 + r)*INNER_ + k0 + kk];
        }
        __syncthreads();
        #pragma unroll
        for (int kk = 0; kk < 16; ++kk) {
            float a[4], b[4];
            #pragma unroll
            for (int i = 0; i < 4; ++i) a[i] = As[ty*4+i][kk];
            #pragma unroll
            for (int j = 0; j < 4; ++j) b[j] = Bs[kk][tx*4+j];
            #pragma unroll
            for (int i = 0; i < 4; ++i)
                #pragma unroll
                for (int j = 0; j < 4; ++j)
                    acc_o[i][j] += a[i]*b[j];
        }
        __syncthreads();
    }

    // X @ Wg^T (K = 1024)
    for (int k0 = 0; k0 < C_; k0 += 16) {
        #pragma unroll
        for (int i = 0; i < 4; ++i) {
            int lin = tid + i*256;
            int r = lin >> 4, kk = lin & 15;
            As[r][kk] = X[(size_t)(row0 + r)*C_ + k0 + kk];
            Bs[kk][r] = Wg[(size_t)(col0 + r)*C_ + k0 + kk];
        }
        __syncthreads();
        #pragma unroll
        for (int kk = 0; kk < 16; ++kk) {
            float a[4], b[4];
            #pragma unroll
            for (int i = 0; i < 4; ++i) a[i] = As[ty*4+i][kk];
            #pragma unroll
            for (int j = 0; j < 4; ++j) b[j] = Bs[kk][tx*4+j];
            #pragma unroll
            for (int i = 0; i < 4; ++i)
                #pragma unroll
                for (int j = 0; j < 4; ++j)
                    acc_g[i][j] += a[i]*b[j];
        }
        __syncthreads();
    }

    #pragma unroll
    for (int i = 0; i < 4; ++i) {
        int r = row0 + ty*4 + i;
        #pragma unroll
        for (int j = 0; j < 4; ++j) {
            int c = col0 + tx*4 + j;
            float gate = 1.f / (1.f + expf(-(acc_g[i][j] + bg[c])));
            float o = acc_o[i][j] + bo[c];
            outp[(size_t)r*C_ + c] = X[(size_t)r*C_ + c] + gate * o;
        }
    }
}

// ---------------------------------------------------------------------------
extern "C" void kernel_launch(void* const* d_in, const int* in_sizes, int n_in,
                              void* d_out, int out_size, void* d_ws, size_t ws_size,
                              hipStream_t stream) {
    const float* query   = (const float*)d_in[0];
    const float* support = (const float*)d_in[1];
    const float* mask    = (const float*)d_in[2];
    const float* ln_q_w  = (const float*)d_in[3];
    const float* ln_q_b  = (const float*)d_in[4];
    const float* ln_s_w  = (const float*)d_in[5];
    const float* ln_s_b  = (const float*)d_in[6];
    const float* Wq      = (const float*)d_in[7];
    const float* bq      = (const float*)d_in[8];
    const float* Wk      = (const float*)d_in[9];
    const float* bk      = (const float*)d_in[10];
    const float* Wv      = (const float*)d_in[11];
    const float* bv      = (const float*)d_in[12];
    const float* Wo      = (const float*)d_in[13];
    const float* bo      = (const float*)d_in[14];
    const float* Wg      = (const float*)d_in[15];
    const float* bg      = (const float*)d_in[16];

    float* out      = (float*)d_out;
    float* attn_out = out + (size_t)M_ * C_;

    float* ws   = (float*)d_ws;
    float* mu_q = ws;
    float* rs_q = mu_q + M_;
    float* mu_s = rs_q + M_;
    float* rs_s = mu_s + M_;
    float* Qb   = rs_s + M_;
    float* Kb   = Qb + (size_t)M_*INNER_;
    float* Vb   = Kb + (size_t)M_*INNER_;
    float* ctx  = Vb + (size_t)M_*INNER_;

    ln_stats_kernel<<<dim3(M_/4), dim3(256), 0, stream>>>(query, mu_q, rs_q);
    ln_stats_kernel<<<dim3(M_/4), dim3(256), 0, stream>>>(support, mu_s, rs_s);

    ln_gemm_kernel<C_><<<dim3(INNER_/64, M_/64), dim3(256), 0, stream>>>(
        query, mu_q, rs_q, ln_q_w, ln_q_b, Wq, bq, Qb, INNER_);
    ln_gemm_kernel<C_><<<dim3(INNER_/64, M_/64), dim3(256), 0, stream>>>(
        support, mu_s, rs_s, ln_s_w, ln_s_b, Wk, bk, Kb, INNER_);
    ln_gemm_kernel<C_><<<dim3(INNER_/64, M_/64), dim3(256), 0, stream>>>(
        support, mu_s, rs_s, ln_s_w, ln_s_b, Wv, bv, Vb, INNER_);

    attn_kernel<<<dim3(N_/16, B_*H_), dim3(256), 0, stream>>>(
        Qb, Kb, Vb, mask, attn_out, ctx);

    final_kernel<<<dim3(C_/64, M_/64), dim3(256), 0, stream>>>(
        ctx, Wo, bo, query, Wg, bg, out);
}

// Round 2
// 1255.526 us; speedup vs baseline: 2.0085x; 2.0085x over previous
//
#include <hip/hip_runtime.h>
#include <hip/hip_bf16.h>
#include <math.h>

#define B_ 32
#define N_ 576
#define C_ 1024
#define INNER_ 256
#define H_ 4
#define HD_ 64
#define M_ (B_*N_)           // 18432
#define ALPHA_ 5.0f
#define EPS_ 1e-5f

typedef __attribute__((ext_vector_type(8))) short bf16x8;
typedef __attribute__((ext_vector_type(4))) float f32x4;
typedef __attribute__((ext_vector_type(4))) unsigned int u32x4;
typedef unsigned short u16;

// ---------------------------------------------------------------------------
// LayerNorm row stats (mean, rstd). One wave per row.
// ---------------------------------------------------------------------------
__global__ void ln_stats_kernel(const float* __restrict__ X,
                                float* __restrict__ mu, float* __restrict__ rs) {
    int row = blockIdx.x * 4 + (threadIdx.x >> 6);
    int lane = threadIdx.x & 63;
    const float* xp = X + (size_t)row * C_;
    float s = 0.f, s2 = 0.f;
    #pragma unroll
    for (int i = 0; i < C_/64; ++i) {
        float v = xp[lane + i*64];
        s += v; s2 += v*v;
    }
    #pragma unroll
    for (int m = 32; m; m >>= 1) {
        s  += __shfl_xor(s,  m, 64);
        s2 += __shfl_xor(s2, m, 64);
    }
    if (lane == 0) {
        float mean = s * (1.f/C_);
        float var  = s2 * (1.f/C_) - mean*mean;
        mu[row] = mean;
        rs[row] = rsqrtf(var + EPS_);
    }
}

// ---------------------------------------------------------------------------
// Apply LN and convert to bf16: out[m][k] = bf16((x-mu)*rs*w + b)
// 8 elems per thread, vectorized.
// ---------------------------------------------------------------------------
__global__ void ln_apply_kernel(const float* __restrict__ X, const float* __restrict__ mu,
                                const float* __restrict__ rs, const float* __restrict__ w,
                                const float* __restrict__ b, u16* __restrict__ out) {
    size_t i = ((size_t)blockIdx.x * 256 + threadIdx.x) * 8;
    int row = (int)(i >> 10);
    int k = (int)(i & 1023);
    float m = mu[row], r = rs[row];
    float4 a0 = *(const float4*)(X + i);
    float4 a1 = *(const float4*)(X + i + 4);
    float4 w0 = *(const float4*)(w + k);
    float4 w1 = *(const float4*)(w + k + 4);
    float4 b0 = *(const float4*)(b + k);
    float4 b1 = *(const float4*)(b + k + 4);
    union { __hip_bfloat16 h[8]; u32x4 v; } o;
    o.h[0] = __float2bfloat16((a0.x - m)*r*w0.x + b0.x);
    o.h[1] = __float2bfloat16((a0.y - m)*r*w0.y + b0.y);
    o.h[2] = __float2bfloat16((a0.z - m)*r*w0.z + b0.z);
    o.h[3] = __float2bfloat16((a0.w - m)*r*w0.w + b0.w);
    o.h[4] = __float2bfloat16((a1.x - m)*r*w1.x + b1.x);
    o.h[5] = __float2bfloat16((a1.y - m)*r*w1.y + b1.y);
    o.h[6] = __float2bfloat16((a1.z - m)*r*w1.z + b1.z);
    o.h[7] = __float2bfloat16((a1.w - m)*r*w1.w + b1.w);
    *(u32x4*)(out + i) = o.v;
}

// ---------------------------------------------------------------------------
// Plain f32 -> bf16 conversion, 8 elems per thread.
// ---------------------------------------------------------------------------
__global__ void cvt_bf16_kernel(const float* __restrict__ in, u16* __restrict__ out) {
    size_t i = ((size_t)blockIdx.x * 256 + threadIdx.x) * 8;
    float4 a0 = *(const float4*)(in + i);
    float4 a1 = *(const float4*)(in + i + 4);
    union { __hip_bfloat16 h[8]; u32x4 v; } o;
    o.h[0] = __float2bfloat16(a0.x); o.h[1] = __float2bfloat16(a0.y);
    o.h[2] = __float2bfloat16(a0.z); o.h[3] = __float2bfloat16(a0.w);
    o.h[4] = __float2bfloat16(a1.x); o.h[5] = __float2bfloat16(a1.y);
    o.h[6] = __float2bfloat16(a1.z); o.h[7] = __float2bfloat16(a1.w);
    *(u32x4*)(out + i) = o.v;
}

// ---------------------------------------------------------------------------
// bf16 MFMA GEMM: Out[m][n] = sum_k A[m][k] * Bw[n][k]  (+ epilogue per MODE)
// 128x128 tile, BK=64, 256 threads = 4 waves (2x2 of 64x64), 4x4 fragments
// of mfma_f32_16x16x32_bf16. LDS rows padded +8 bf16 to break bank conflicts.
// MODE 0: out bf16 = acc + bias
// MODE 1: out bf16 = sigmoid(acc + bias)
// MODE 2: out f32  = Xres + gate * (acc + bias)
// ---------------------------------------------------------------------------
template<int NOUT, int KDIM, int MODE>
__global__ __launch_bounds__(256, 2)
void mfma_gemm_kernel(const u16* __restrict__ A, const u16* __restrict__ Bw,
                      const float* __restrict__ bias,
                      const float* __restrict__ Xres,
                      const __hip_bfloat16* __restrict__ gate,
                      void* __restrict__ OutP) {
    __shared__ u16 Asm[128][72];
    __shared__ u16 Bsm[128][72];
    int tid = threadIdx.x;
    int lane = tid & 63, wid = tid >> 6;
    int wm = (wid >> 1) * 64, wn = (wid & 1) * 64;
    int row0 = blockIdx.y * 128, col0 = blockIdx.x * 128;
    f32x4 acc[4][4] = {};

    for (int k0 = 0; k0 < KDIM; k0 += 64) {
        #pragma unroll
        for (int i = 0; i < 4; ++i) {
            int s = tid + i*256;
            int r = s >> 3, cg = (s & 7) * 8;
            u32x4 va = *(const u32x4*)(A  + (size_t)(row0 + r)*KDIM + k0 + cg);
            u32x4 vb = *(const u32x4*)(Bw + (size_t)(col0 + r)*KDIM + k0 + cg);
            *(u32x4*)&Asm[r][cg] = va;
            *(u32x4*)&Bsm[r][cg] = vb;
        }
        __syncthreads();
        #pragma unroll
        for (int ks = 0; ks < 64; ks += 32) {
            bf16x8 af[4], bfr[4];
            #pragma unroll
            for (int i = 0; i < 4; ++i)
                af[i] = *(const bf16x8*)&Asm[wm + i*16 + (lane & 15)][ks + (lane >> 4)*8];
            #pragma unroll
            for (int j = 0; j < 4; ++j)
                bfr[j] = *(const bf16x8*)&Bsm[wn + j*16 + (lane & 15)][ks + (lane >> 4)*8];
            #pragma unroll
            for (int i = 0; i < 4; ++i)
                #pragma unroll
                for (int j = 0; j < 4; ++j)
                    acc[i][j] = __builtin_amdgcn_mfma_f32_16x16x32_bf16(
                        af[i], bfr[j], acc[i][j], 0, 0, 0);
        }
        __syncthreads();
    }

    #pragma unroll
    for (int i = 0; i < 4; ++i) {
        #pragma unroll
        for (int j = 0; j < 4; ++j) {
            int col = col0 + wn + j*16 + (lane & 15);
            float bb = bias[col];
            #pragma unroll
            for (int r = 0; r < 4; ++r) {
                int row = row0 + wm + i*16 + (lane >> 4)*4 + r;
                float v = acc[i][j][r] + bb;
                size_t idx = (size_t)row * NOUT + col;
                if (MODE == 0) {
                    ((__hip_bfloat16*)OutP)[idx] = __float2bfloat16(v);
                } else if (MODE == 1) {
                    float g = 1.f / (1.f + expf(-v));
                    ((__hip_bfloat16*)OutP)[idx] = __float2bfloat16(g);
                } else {
                    float g = __bfloat162float(gate[idx]);
                    ((float*)OutP)[idx] = Xres[idx] + g * v;
                }
            }
        }
    }
}

// ---------------------------------------------------------------------------
// Attention: one (b,h), 16 q-rows per block. bf16 Q/K/V in, attn f32 out,
// ctx bf16 out.
// ---------------------------------------------------------------------------
__global__ void attn_kernel(const __hip_bfloat16* __restrict__ Qb,
                            const __hip_bfloat16* __restrict__ Kb,
                            const __hip_bfloat16* __restrict__ Vb,
                            const float* __restrict__ mask,
                            float* __restrict__ attn_out,
                            __hip_bfloat16* __restrict__ ctx) {
    __shared__ float Qs[16][HD_];
    __shared__ float Ks[16][HD_+1];
    __shared__ float S[16][N_];
    int tid = threadIdx.x;
    int bh = blockIdx.y;
    int b = bh >> 2, h = bh & 3;
    int q0 = blockIdx.x * 16;

    #pragma unroll
    for (int i = 0; i < 4; ++i) {
        int lin = tid + i*256;
        int r = lin >> 6, d = lin & 63;
        Qs[r][d] = __bfloat162float(Qb[(size_t)(b*N_ + q0 + r) * INNER_ + h*HD_ + d]);
    }
    __syncthreads();

    int rr = tid >> 4, jl = tid & 15;
    for (int j0 = 0; j0 < N_; j0 += 16) {
        #pragma unroll
        for (int i = 0; i < 4; ++i) {
            int lin = tid + i*256;
            int r = lin >> 6, d = lin & 63;
            Ks[r][d] = __bfloat162float(Kb[(size_t)(b*N_ + j0 + r) * INNER_ + h*HD_ + d]);
        }
        __syncthreads();
        float s = 0.f;
        #pragma unroll
        for (int d = 0; d < HD_; ++d) s += Qs[rr][d]*Ks[jl][d];
        S[rr][j0 + jl] = s * 0.125f + ALPHA_ * mask[b*N_ + j0 + jl];
        __syncthreads();
    }

    {
        int r = tid >> 4, l = tid & 15;
        float m = -1e30f;
        for (int t = l; t < N_; t += 16) m = fmaxf(m, S[r][t]);
        #pragma unroll
        for (int msk = 8; msk; msk >>= 1) m = fmaxf(m, __shfl_xor(m, msk, 16));
        float sum = 0.f;
        for (int t = l; t < N_; t += 16) { float e = expf(S[r][t] - m); S[r][t] = e; sum += e; }
        #pragma unroll
        for (int msk = 8; msk; msk >>= 1) sum += __shfl_xor(sum, msk, 16);
        float inv = 1.f / sum;
        for (int t = l; t < N_; t += 16) S[r][t] *= inv;
    }
    __syncthreads();

    float* ap = attn_out + ((size_t)bh * N_ + q0) * N_;
    for (int idx = tid; idx < 16*N_; idx += 256) {
        int r = idx / N_;
        int t = idx - r*N_;
        ap[(size_t)r*N_ + t] = S[r][t];
    }

    float acc[4] = {0.f,0.f,0.f,0.f};
    int dl = tid & 15;
    for (int j0 = 0; j0 < N_; j0 += 16) {
        __syncthreads();
        #pragma unroll
        for (int i = 0; i < 4; ++i) {
            int lin = tid + i*256;
            int r = lin >> 6, d = lin & 63;
            Ks[r][d] = __bfloat162float(Vb[(size_t)(b*N_ + j0 + r) * INNER_ + h*HD_ + d]);
        }
        __syncthreads();
        #pragma unroll
        for (int jj = 0; jj < 16; ++jj) {
            float p = S[rr][j0+jj];
            #pragma unroll
            for (int i = 0; i < 4; ++i)
                acc[i] += p * Ks[jj][dl + 16*i];
        }
    }
    #pragma unroll
    for (int i = 0; i < 4; ++i)
        ctx[(size_t)(b*N_ + q0 + rr) * INNER_ + h*HD_ + dl + 16*i] = __float2bfloat16(acc[i]);
}

// ---------------------------------------------------------------------------
extern "C" void kernel_launch(void* const* d_in, const int* in_sizes, int n_in,
                              void* d_out, int out_size, void* d_ws, size_t ws_size,
                              hipStream_t stream) {
    const float* query   = (const float*)d_in[0];
    const float* support = (const float*)d_in[1];
    const float* mask    = (const float*)d_in[2];
    const float* ln_q_w  = (const float*)d_in[3];
    const float* ln_q_b  = (const float*)d_in[4];
    const float* ln_s_w  = (const float*)d_in[5];
    const float* ln_s_b  = (const float*)d_in[6];
    const float* Wq      = (const float*)d_in[7];
    const float* bq      = (const float*)d_in[8];
    const float* Wk      = (const float*)d_in[9];
    const float* bk      = (const float*)d_in[10];
    const float* Wv      = (const float*)d_in[11];
    const float* bv      = (const float*)d_in[12];
    const float* Wo      = (const float*)d_in[13];
    const float* bo      = (const float*)d_in[14];
    const float* Wg      = (const float*)d_in[15];
    const float* bg      = (const float*)d_in[16];

    float* out      = (float*)d_out;
    float* attn_out = out + (size_t)M_ * C_;

    char* w = (char*)d_ws;
    float* mu_q = (float*)w;             w += (size_t)M_*4;
    float* rs_q = (float*)w;             w += (size_t)M_*4;
    float* mu_s = (float*)w;             w += (size_t)M_*4;
    float* rs_s = (float*)w;             w += (size_t)M_*4;
    u16* Aq   = (u16*)w;                 w += (size_t)M_*C_*2;      // aliased by gate later
    u16* As_  = (u16*)w;                 w += (size_t)M_*C_*2;      // aliased by Xq later
    u16* Wq_b = (u16*)w;                 w += (size_t)INNER_*C_*2;
    u16* Wk_b = (u16*)w;                 w += (size_t)INNER_*C_*2;
    u16* Wv_b = (u16*)w;                 w += (size_t)INNER_*C_*2;
    u16* Wo_b = (u16*)w;                 w += (size_t)C_*INNER_*2;
    u16* Wg_b = (u16*)w;                 w += (size_t)C_*C_*2;
    u16* Qbf  = (u16*)w;                 w += (size_t)M_*INNER_*2;
    u16* Kbf  = (u16*)w;                 w += (size_t)M_*INNER_*2;
    u16* Vbf  = (u16*)w;                 w += (size_t)M_*INNER_*2;
    u16* ctxb = (u16*)w;                 w += (size_t)M_*INNER_*2;
    u16* gate_b = Aq;   // Aq dead after Q gemm
    u16* Xq     = As_;  // As_ dead after V gemm

    // LN stats
    ln_stats_kernel<<<dim3(M_/4), dim3(256), 0, stream>>>(query, mu_q, rs_q);
    ln_stats_kernel<<<dim3(M_/4), dim3(256), 0, stream>>>(support, mu_s, rs_s);

    // LN-applied bf16 activations
    ln_apply_kernel<<<dim3(M_*C_/2048), dim3(256), 0, stream>>>(query,   mu_q, rs_q, ln_q_w, ln_q_b, Aq);
    ln_apply_kernel<<<dim3(M_*C_/2048), dim3(256), 0, stream>>>(support, mu_s, rs_s, ln_s_w, ln_s_b, As_);

    // weight conversions
    cvt_bf16_kernel<<<dim3(INNER_*C_/2048), dim3(256), 0, stream>>>(Wq, Wq_b);
    cvt_bf16_kernel<<<dim3(INNER_*C_/2048), dim3(256), 0, stream>>>(Wk, Wk_b);
    cvt_bf16_kernel<<<dim3(INNER_*C_/2048), dim3(256), 0, stream>>>(Wv, Wv_b);
    cvt_bf16_kernel<<<dim3(C_*INNER_/2048), dim3(256), 0, stream>>>(Wo, Wo_b);
    cvt_bf16_kernel<<<dim3(C_*C_/2048),     dim3(256), 0, stream>>>(Wg, Wg_b);

    // QKV projections (bf16 MFMA)
    mfma_gemm_kernel<INNER_, C_, 0><<<dim3(INNER_/128, M_/128), dim3(256), 0, stream>>>(
        Aq,  Wq_b, bq, nullptr, nullptr, Qbf);
    mfma_gemm_kernel<INNER_, C_, 0><<<dim3(INNER_/128, M_/128), dim3(256), 0, stream>>>(
        As_, Wk_b, bk, nullptr, nullptr, Kbf);
    mfma_gemm_kernel<INNER_, C_, 0><<<dim3(INNER_/128, M_/128), dim3(256), 0, stream>>>(
        As_, Wv_b, bv, nullptr, nullptr, Vbf);

    // raw query as bf16 (for gate GEMM) — As_ region now dead
    cvt_bf16_kernel<<<dim3(M_*C_/2048), dim3(256), 0, stream>>>(query, Xq);

    // attention
    attn_kernel<<<dim3(N_/16, B_*H_), dim3(256), 0, stream>>>(
        (const __hip_bfloat16*)Qbf, (const __hip_bfloat16*)Kbf,
        (const __hip_bfloat16*)Vbf, mask, attn_out, (__hip_bfloat16*)ctxb);

    // gate = sigmoid(X @ Wg^T + bg)  (bf16 out) — Aq region now dead
    mfma_gemm_kernel<C_, C_, 1><<<dim3(C_/128, M_/128), dim3(256), 0, stream>>>(
        Xq, Wg_b, bg, nullptr, nullptr, gate_b);

    // enhanced = X + gate * (ctx @ Wo^T + bo)
    mfma_gemm_kernel<C_, INNER_, 2><<<dim3(C_/128, M_/128), dim3(256), 0, stream>>>(
        ctxb, Wo_b, bo, query, (const __hip_bfloat16*)gate_b, out);
}

// Round 3
// 506.997 us; speedup vs baseline: 4.9739x; 2.4764x over previous
//
#include <hip/hip_runtime.h>
#include <hip/hip_bf16.h>
#include <math.h>

#define B_ 32
#define N_ 576
#define C_ 1024
#define INNER_ 256
#define H_ 4
#define HD_ 64
#define M_ (B_*N_)           // 18432
#define ALPHA_ 5.0f
#define EPS_ 1e-5f

typedef __attribute__((ext_vector_type(8))) short bf16x8;
typedef __attribute__((ext_vector_type(4))) float f32x4;
typedef __attribute__((ext_vector_type(4))) unsigned int u32x4;
typedef unsigned short u16;

__device__ inline u16 bfbits(float x) {
    union { __hip_bfloat16 h; u16 u; } c; c.h = __float2bfloat16(x); return c.u;
}
__device__ inline unsigned pack2bf(float a, float b) {
    return (unsigned)bfbits(a) | ((unsigned)bfbits(b) << 16);
}

// ---------------------------------------------------------------------------
// LayerNorm row stats (mean, rstd). One wave per row.
// ---------------------------------------------------------------------------
__global__ void ln_stats_kernel(const float* __restrict__ X,
                                float* __restrict__ mu, float* __restrict__ rs) {
    int row = blockIdx.x * 4 + (threadIdx.x >> 6);
    int lane = threadIdx.x & 63;
    const float* xp = X + (size_t)row * C_;
    float s = 0.f, s2 = 0.f;
    #pragma unroll
    for (int i = 0; i < C_/64; ++i) {
        float v = xp[lane + i*64];
        s += v; s2 += v*v;
    }
    #pragma unroll
    for (int m = 32; m; m >>= 1) {
        s  += __shfl_xor(s,  m, 64);
        s2 += __shfl_xor(s2, m, 64);
    }
    if (lane == 0) {
        float mean = s * (1.f/C_);
        float var  = s2 * (1.f/C_) - mean*mean;
        mu[row] = mean;
        rs[row] = rsqrtf(var + EPS_);
    }
}

// ---------------------------------------------------------------------------
// Apply LN and convert to bf16.
// ---------------------------------------------------------------------------
__global__ void ln_apply_kernel(const float* __restrict__ X, const float* __restrict__ mu,
                                const float* __restrict__ rs, const float* __restrict__ w,
                                const float* __restrict__ b, u16* __restrict__ out) {
    size_t i = ((size_t)blockIdx.x * 256 + threadIdx.x) * 8;
    int row = (int)(i >> 10);
    int k = (int)(i & 1023);
    float m = mu[row], r = rs[row];
    float4 a0 = *(const float4*)(X + i);
    float4 a1 = *(const float4*)(X + i + 4);
    float4 w0 = *(const float4*)(w + k);
    float4 w1 = *(const float4*)(w + k + 4);
    float4 b0 = *(const float4*)(b + k);
    float4 b1 = *(const float4*)(b + k + 4);
    union { __hip_bfloat16 h[8]; u32x4 v; } o;
    o.h[0] = __float2bfloat16((a0.x - m)*r*w0.x + b0.x);
    o.h[1] = __float2bfloat16((a0.y - m)*r*w0.y + b0.y);
    o.h[2] = __float2bfloat16((a0.z - m)*r*w0.z + b0.z);
    o.h[3] = __float2bfloat16((a0.w - m)*r*w0.w + b0.w);
    o.h[4] = __float2bfloat16((a1.x - m)*r*w1.x + b1.x);
    o.h[5] = __float2bfloat16((a1.y - m)*r*w1.y + b1.y);
    o.h[6] = __float2bfloat16((a1.z - m)*r*w1.z + b1.z);
    o.h[7] = __float2bfloat16((a1.w - m)*r*w1.w + b1.w);
    *(u32x4*)(out + i) = o.v;
}

// ---------------------------------------------------------------------------
// Plain f32 -> bf16 conversion.
// ---------------------------------------------------------------------------
__global__ void cvt_bf16_kernel(const float* __restrict__ in, u16* __restrict__ out) {
    size_t i = ((size_t)blockIdx.x * 256 + threadIdx.x) * 8;
    float4 a0 = *(const float4*)(in + i);
    float4 a1 = *(const float4*)(in + i + 4);
    union { __hip_bfloat16 h[8]; u32x4 v; } o;
    o.h[0] = __float2bfloat16(a0.x); o.h[1] = __float2bfloat16(a0.y);
    o.h[2] = __float2bfloat16(a0.z); o.h[3] = __float2bfloat16(a0.w);
    o.h[4] = __float2bfloat16(a1.x); o.h[5] = __float2bfloat16(a1.y);
    o.h[6] = __float2bfloat16(a1.z); o.h[7] = __float2bfloat16(a1.w);
    *(u32x4*)(out + i) = o.v;
}

// ---------------------------------------------------------------------------
// bf16 MFMA GEMM (same as round 2 — validated).
// ---------------------------------------------------------------------------
template<int NOUT, int KDIM, int MODE>
__global__ __launch_bounds__(256, 2)
void mfma_gemm_kernel(const u16* __restrict__ A, const u16* __restrict__ Bw,
                      const float* __restrict__ bias,
                      const float* __restrict__ Xres,
                      const __hip_bfloat16* __restrict__ gate,
                      void* __restrict__ OutP) {
    __shared__ u16 Asm[128][72];
    __shared__ u16 Bsm[128][72];
    int tid = threadIdx.x;
    int lane = tid & 63, wid = tid >> 6;
    int wm = (wid >> 1) * 64, wn = (wid & 1) * 64;
    int row0 = blockIdx.y * 128, col0 = blockIdx.x * 128;
    f32x4 acc[4][4] = {};

    for (int k0 = 0; k0 < KDIM; k0 += 64) {
        #pragma unroll
        for (int i = 0; i < 4; ++i) {
            int s = tid + i*256;
            int r = s >> 3, cg = (s & 7) * 8;
            u32x4 va = *(const u32x4*)(A  + (size_t)(row0 + r)*KDIM + k0 + cg);
            u32x4 vb = *(const u32x4*)(Bw + (size_t)(col0 + r)*KDIM + k0 + cg);
            *(u32x4*)&Asm[r][cg] = va;
            *(u32x4*)&Bsm[r][cg] = vb;
        }
        __syncthreads();
        #pragma unroll
        for (int ks = 0; ks < 64; ks += 32) {
            bf16x8 af[4], bfr[4];
            #pragma unroll
            for (int i = 0; i < 4; ++i)
                af[i] = *(const bf16x8*)&Asm[wm + i*16 + (lane & 15)][ks + (lane >> 4)*8];
            #pragma unroll
            for (int j = 0; j < 4; ++j)
                bfr[j] = *(const bf16x8*)&Bsm[wn + j*16 + (lane & 15)][ks + (lane >> 4)*8];
            #pragma unroll
            for (int i = 0; i < 4; ++i)
                #pragma unroll
                for (int j = 0; j < 4; ++j)
                    acc[i][j] = __builtin_amdgcn_mfma_f32_16x16x32_bf16(
                        af[i], bfr[j], acc[i][j], 0, 0, 0);
        }
        __syncthreads();
    }

    #pragma unroll
    for (int i = 0; i < 4; ++i) {
        #pragma unroll
        for (int j = 0; j < 4; ++j) {
            int col = col0 + wn + j*16 + (lane & 15);
            float bb = bias[col];
            #pragma unroll
            for (int r = 0; r < 4; ++r) {
                int row = row0 + wm + i*16 + (lane >> 4)*4 + r;
                float v = acc[i][j][r] + bb;
                size_t idx = (size_t)row * NOUT + col;
                if (MODE == 0) {
                    ((__hip_bfloat16*)OutP)[idx] = __float2bfloat16(v);
                } else if (MODE == 1) {
                    float g = 1.f / (1.f + expf(-v));
                    ((__hip_bfloat16*)OutP)[idx] = __float2bfloat16(g);
                } else {
                    float g = __bfloat162float(gate[idx]);
                    ((float*)OutP)[idx] = Xres[idx] + g * v;
                }
            }
        }
    }
}

// ---------------------------------------------------------------------------
// MFMA attention. Block = 4 waves, one (b,h), 64 q-rows (16 per wave).
// Swapped QK^T -> S^T in regs (lane: q=lane&15, k=(lane>>4)*4+r per tile).
// In-register softmax. Attn write f32. PV swapped with V^T staged in LDS
// (two 288-k halves); P^T B-frags built via shuffles.
// ---------------------------------------------------------------------------
__device__ inline void stage_v_half(const u16* __restrict__ Vbf, u16* __restrict__ Vt,
                                    int b, int h, int HF, int tid) {
    #pragma unroll
    for (int i = 0; i < 9; ++i) {
        int c = tid + i*256;
        int k = c >> 3;            // 0..287
        int d0 = (c & 7) * 8;
        union { u32x4 v; u16 s[8]; } u;
        u.v = *(const u32x4*)(Vbf + ((size_t)(b*N_ + HF*288 + k))*INNER_ + h*HD_ + d0);
        #pragma unroll
        for (int e = 0; e < 8; ++e)
            Vt[(d0 + e)*296 + k] = u.s[e];
    }
}

template<int HF>
__device__ inline void pv_half(const unsigned (&pk)[36][2], f32x4 (&cacc)[4],
                               const u16* __restrict__ Vt, int lane) {
    int s1 = (lane & 15) + ((lane & 16) << 1);   // q + 32*(g&1)
    int s2 = s1 + 16;
    bool hi = (lane & 32) != 0;
    #pragma unroll
    for (int t9 = 0; t9 < 9; ++t9) {
        const int t = HF*9 + t9;
        unsigned A01 = __shfl((int)pk[2*t  ][0], s1, 64);
        unsigned A23 = __shfl((int)pk[2*t  ][1], s1, 64);
        unsigned B01 = __shfl((int)pk[2*t+1][0], s1, 64);
        unsigned B23 = __shfl((int)pk[2*t+1][1], s1, 64);
        unsigned C01 = __shfl((int)pk[2*t  ][0], s2, 64);
        unsigned C23 = __shfl((int)pk[2*t  ][1], s2, 64);
        unsigned D01 = __shfl((int)pk[2*t+1][0], s2, 64);
        unsigned D23 = __shfl((int)pk[2*t+1][1], s2, 64);
        union { unsigned w[4]; bf16x8 v; } bu;
        bu.w[0] = hi ? B01 : A01;
        bu.w[1] = hi ? B23 : A23;
        bu.w[2] = hi ? D01 : C01;
        bu.w[3] = hi ? D23 : C23;
        int colb = 32*t - 288*HF + 8*(lane >> 4);
        #pragma unroll
        for (int dt = 0; dt < 4; ++dt) {
            bf16x8 a = *(const bf16x8*)&Vt[(16*dt + (lane & 15))*296 + colb];
            cacc[dt] = __builtin_amdgcn_mfma_f32_16x16x32_bf16(a, bu.v, cacc[dt], 0, 0, 0);
        }
    }
}

__global__ __launch_bounds__(256, 2)
void attn_mfma_kernel(const u16* __restrict__ Qbf, const u16* __restrict__ Kbf,
                      const u16* __restrict__ Vbf, const float* __restrict__ mask,
                      float* __restrict__ attn_out, u16* __restrict__ ctxb) {
    __shared__ u16 Vt[64*296];
    __shared__ float Msk[576];
    int tid = threadIdx.x;
    int lane = tid & 63, wid = tid >> 6;
    int bh = blockIdx.y, b = bh >> 2, h = bh & 3;
    int q0 = blockIdx.x * 64;
    int g = lane >> 4;
    int qrow = q0 + wid*16 + (lane & 15);

    if (tid < 144) {
        float4 mv = *(const float4*)(mask + b*N_ + tid*4);
        *(float4*)&Msk[tid*4] = make_float4(ALPHA_*mv.x, ALPHA_*mv.y, ALPHA_*mv.z, ALPHA_*mv.w);
    }
    stage_v_half(Vbf, Vt, b, h, 0, tid);
    __syncthreads();

    // Q fragments (B-operand): lane holds Q[q=lane&15][d=g*8+j], d-chunks 0,32
    const u16* qp = Qbf + ((size_t)(b*N_) + qrow)*INNER_ + h*HD_ + g*8;
    bf16x8 qf0 = *(const bf16x8*)qp;
    bf16x8 qf1 = *(const bf16x8*)(qp + 32);

    // QK^T: 36 k-tiles of 16, A = K-tile loaded direct from global
    f32x4 acc[36];
    #pragma unroll
    for (int T = 0; T < 36; ++T) acc[T] = (f32x4){0.f, 0.f, 0.f, 0.f};

    const u16* kp = Kbf + ((size_t)(b*N_) + (lane & 15))*INNER_ + h*HD_ + g*8;
    bf16x8 kb[2][2];
    kb[0][0] = *(const bf16x8*)(kp);
    kb[0][1] = *(const bf16x8*)(kp + 32);
    kb[1][0] = *(const bf16x8*)(kp + 16*INNER_);
    kb[1][1] = *(const bf16x8*)(kp + 16*INNER_ + 32);
    #pragma unroll
    for (int T = 0; T < 36; ++T) {
        bf16x8 n0, n1;
        if (T + 2 < 36) {
            n0 = *(const bf16x8*)(kp + (size_t)(T+2)*16*INNER_);
            n1 = *(const bf16x8*)(kp + (size_t)(T+2)*16*INNER_ + 32);
        }
        acc[T] = __builtin_amdgcn_mfma_f32_16x16x32_bf16(kb[T&1][0], qf0, acc[T], 0, 0, 0);
        acc[T] = __builtin_amdgcn_mfma_f32_16x16x32_bf16(kb[T&1][1], qf1, acc[T], 0, 0, 0);
        if (T + 2 < 36) { kb[T&1][0] = n0; kb[T&1][1] = n1; }
    }

    // scale + mask + row max
    float m = -1e30f;
    #pragma unroll
    for (int T = 0; T < 36; ++T) {
        float4 mk = *(const float4*)&Msk[16*T + 4*g];
        acc[T][0] = acc[T][0]*0.125f + mk.x;
        acc[T][1] = acc[T][1]*0.125f + mk.y;
        acc[T][2] = acc[T][2]*0.125f + mk.z;
        acc[T][3] = acc[T][3]*0.125f + mk.w;
        m = fmaxf(m, fmaxf(fmaxf(acc[T][0], acc[T][1]), fmaxf(acc[T][2], acc[T][3])));
    }
    m = fmaxf(m, __shfl_xor(m, 16, 64));
    m = fmaxf(m, __shfl_xor(m, 32, 64));

    // exp + sum
    float l = 0.f;
    #pragma unroll
    for (int T = 0; T < 36; ++T) {
        acc[T][0] = expf(acc[T][0] - m);
        acc[T][1] = expf(acc[T][1] - m);
        acc[T][2] = expf(acc[T][2] - m);
        acc[T][3] = expf(acc[T][3] - m);
        l += acc[T][0] + acc[T][1] + acc[T][2] + acc[T][3];
    }
    l += __shfl_xor(l, 16, 64);
    l += __shfl_xor(l, 32, 64);
    float inv = 1.f / l;

    // write attn (f32, normalized) + pack P to bf16
    unsigned pk[36][2];
    float* ap = attn_out + ((size_t)bh*N_ + qrow)*N_;
    #pragma unroll
    for (int T = 0; T < 36; ++T) {
        float e0 = acc[T][0]*inv, e1 = acc[T][1]*inv;
        float e2 = acc[T][2]*inv, e3 = acc[T][3]*inv;
        *(float4*)(ap + 16*T + 4*g) = make_float4(e0, e1, e2, e3);
        pk[T][0] = pack2bf(e0, e1);
        pk[T][1] = pack2bf(e2, e3);
    }

    // PV: ctx^T = V^T @ P^T, two k-halves
    f32x4 cacc[4] = {};
    pv_half<0>(pk, cacc, Vt, lane);
    __syncthreads();
    stage_v_half(Vbf, Vt, b, h, 1, tid);
    __syncthreads();
    pv_half<1>(pk, cacc, Vt, lane);

    // ctx write: lane holds d = 16*dt + 4*g + r for its q
    u16* cp = ctxb + ((size_t)(b*N_) + qrow)*INNER_ + h*HD_ + 4*g;
    #pragma unroll
    for (int dt = 0; dt < 4; ++dt) {
        ushort4 o;
        o.x = bfbits(cacc[dt][0]);
        o.y = bfbits(cacc[dt][1]);
        o.z = bfbits(cacc[dt][2]);
        o.w = bfbits(cacc[dt][3]);
        *(ushort4*)(cp + 16*dt) = o;
    }
}

// ---------------------------------------------------------------------------
extern "C" void kernel_launch(void* const* d_in, const int* in_sizes, int n_in,
                              void* d_out, int out_size, void* d_ws, size_t ws_size,
                              hipStream_t stream) {
    const float* query   = (const float*)d_in[0];
    const float* support = (const float*)d_in[1];
    const float* mask    = (const float*)d_in[2];
    const float* ln_q_w  = (const float*)d_in[3];
    const float* ln_q_b  = (const float*)d_in[4];
    const float* ln_s_w  = (const float*)d_in[5];
    const float* ln_s_b  = (const float*)d_in[6];
    const float* Wq      = (const float*)d_in[7];
    const float* bq      = (const float*)d_in[8];
    const float* Wk      = (const float*)d_in[9];
    const float* bk      = (const float*)d_in[10];
    const float* Wv      = (const float*)d_in[11];
    const float* bv      = (const float*)d_in[12];
    const float* Wo      = (const float*)d_in[13];
    const float* bo      = (const float*)d_in[14];
    const float* Wg      = (const float*)d_in[15];
    const float* bg      = (const float*)d_in[16];

    float* out      = (float*)d_out;
    float* attn_out = out + (size_t)M_ * C_;

    char* w = (char*)d_ws;
    float* mu_q = (float*)w;             w += (size_t)M_*4;
    float* rs_q = (float*)w;             w += (size_t)M_*4;
    float* mu_s = (float*)w;             w += (size_t)M_*4;
    float* rs_s = (float*)w;             w += (size_t)M_*4;
    u16* Aq   = (u16*)w;                 w += (size_t)M_*C_*2;
    u16* As_  = (u16*)w;                 w += (size_t)M_*C_*2;
    u16* Wq_b = (u16*)w;                 w += (size_t)INNER_*C_*2;
    u16* Wk_b = (u16*)w;                 w += (size_t)INNER_*C_*2;
    u16* Wv_b = (u16*)w;                 w += (size_t)INNER_*C_*2;
    u16* Wo_b = (u16*)w;                 w += (size_t)C_*INNER_*2;
    u16* Wg_b = (u16*)w;                 w += (size_t)C_*C_*2;
    u16* Qbf  = (u16*)w;                 w += (size_t)M_*INNER_*2;
    u16* Kbf  = (u16*)w;                 w += (size_t)M_*INNER_*2;
    u16* Vbf  = (u16*)w;                 w += (size_t)M_*INNER_*2;
    u16* ctxb = (u16*)w;                 w += (size_t)M_*INNER_*2;
    u16* gate_b = Aq;   // Aq dead after Q gemm
    u16* Xq     = As_;  // As_ dead after V gemm

    ln_stats_kernel<<<dim3(M_/4), dim3(256), 0, stream>>>(query, mu_q, rs_q);
    ln_stats_kernel<<<dim3(M_/4), dim3(256), 0, stream>>>(support, mu_s, rs_s);

    ln_apply_kernel<<<dim3(M_*C_/2048), dim3(256), 0, stream>>>(query,   mu_q, rs_q, ln_q_w, ln_q_b, Aq);
    ln_apply_kernel<<<dim3(M_*C_/2048), dim3(256), 0, stream>>>(support, mu_s, rs_s, ln_s_w, ln_s_b, As_);

    cvt_bf16_kernel<<<dim3(INNER_*C_/2048), dim3(256), 0, stream>>>(Wq, Wq_b);
    cvt_bf16_kernel<<<dim3(INNER_*C_/2048), dim3(256), 0, stream>>>(Wk, Wk_b);
    cvt_bf16_kernel<<<dim3(INNER_*C_/2048), dim3(256), 0, stream>>>(Wv, Wv_b);
    cvt_bf16_kernel<<<dim3(C_*INNER_/2048), dim3(256), 0, stream>>>(Wo, Wo_b);
    cvt_bf16_kernel<<<dim3(C_*C_/2048),     dim3(256), 0, stream>>>(Wg, Wg_b);

    mfma_gemm_kernel<INNER_, C_, 0><<<dim3(INNER_/128, M_/128), dim3(256), 0, stream>>>(
        Aq,  Wq_b, bq, nullptr, nullptr, Qbf);
    mfma_gemm_kernel<INNER_, C_, 0><<<dim3(INNER_/128, M_/128), dim3(256), 0, stream>>>(
        As_, Wk_b, bk, nullptr, nullptr, Kbf);
    mfma_gemm_kernel<INNER_, C_, 0><<<dim3(INNER_/128, M_/128), dim3(256), 0, stream>>>(
        As_, Wv_b, bv, nullptr, nullptr, Vbf);

    cvt_bf16_kernel<<<dim3(M_*C_/2048), dim3(256), 0, stream>>>(query, Xq);

    attn_mfma_kernel<<<dim3(N_/64, B_*H_), dim3(256), 0, stream>>>(
        Qbf, Kbf, Vbf, mask, attn_out, ctxb);

    mfma_gemm_kernel<C_, C_, 1><<<dim3(C_/128, M_/128), dim3(256), 0, stream>>>(
        Xq, Wg_b, bg, nullptr, nullptr, gate_b);

    mfma_gemm_kernel<C_, INNER_, 2><<<dim3(C_/128, M_/128), dim3(256), 0, stream>>>(
        ctxb, Wo_b, bo, query, (const __hip_bfloat16*)gate_b, out);
}

// Round 4
// 368.405 us; speedup vs baseline: 6.8451x; 1.3762x over previous
//
#include <hip/hip_runtime.h>
#include <hip/hip_bf16.h>
#include <math.h>

#define B_ 32
#define N_ 576
#define C_ 1024
#define INNER_ 256
#define H_ 4
#define HD_ 64
#define M_ (B_*N_)           // 18432
#define ALPHA_ 5.0f
#define EPS_ 1e-5f

typedef __attribute__((ext_vector_type(8))) short bf16x8;
typedef __attribute__((ext_vector_type(4))) float f32x4;
typedef __attribute__((ext_vector_type(4))) unsigned int u32x4;
typedef unsigned short u16;

__device__ inline u16 bfbits(float x) {
    union { __hip_bfloat16 h; u16 u; } c; c.h = __float2bfloat16(x); return c.u;
}
__device__ inline unsigned pack2bf(float a, float b) {
    return (unsigned)bfbits(a) | ((unsigned)bfbits(b) << 16);
}

// ---------------------------------------------------------------------------
// Fused LayerNorm: one wave per row. Stats via shfl butterfly, apply + bf16
// write in the same pass. Optionally also writes the raw input as bf16.
// ---------------------------------------------------------------------------
template<int WRITE_RAW>
__global__ void ln_fused_kernel(const float* __restrict__ X, const float* __restrict__ w,
                                const float* __restrict__ b, u16* __restrict__ outln,
                                u16* __restrict__ outraw) {
    int row = blockIdx.x * 4 + (threadIdx.x >> 6);
    int lane = threadIdx.x & 63;
    const float* xp = X + (size_t)row * C_;
    float4 v[4];
    #pragma unroll
    for (int j = 0; j < 4; ++j) v[j] = *(const float4*)(xp + lane*4 + j*256);
    float s = 0.f, s2 = 0.f;
    #pragma unroll
    for (int j = 0; j < 4; ++j) {
        s  += v[j].x + v[j].y + v[j].z + v[j].w;
        s2 += v[j].x*v[j].x + v[j].y*v[j].y + v[j].z*v[j].z + v[j].w*v[j].w;
    }
    #pragma unroll
    for (int m = 32; m; m >>= 1) {
        s  += __shfl_xor(s,  m, 64);
        s2 += __shfl_xor(s2, m, 64);
    }
    float mean = s * (1.f/C_);
    float rs = rsqrtf(s2 * (1.f/C_) - mean*mean + EPS_);
    #pragma unroll
    for (int j = 0; j < 4; ++j) {
        int k = lane*4 + j*256;
        float4 wv = *(const float4*)(w + k);
        float4 bv = *(const float4*)(b + k);
        ushort4 o;
        o.x = bfbits((v[j].x - mean)*rs*wv.x + bv.x);
        o.y = bfbits((v[j].y - mean)*rs*wv.y + bv.y);
        o.z = bfbits((v[j].z - mean)*rs*wv.z + bv.z);
        o.w = bfbits((v[j].w - mean)*rs*wv.w + bv.w);
        *(ushort4*)(outln + (size_t)row*C_ + k) = o;
        if (WRITE_RAW) {
            ushort4 r4;
            r4.x = bfbits(v[j].x); r4.y = bfbits(v[j].y);
            r4.z = bfbits(v[j].z); r4.w = bfbits(v[j].w);
            *(ushort4*)(outraw + (size_t)row*C_ + k) = r4;
        }
    }
}

// ---------------------------------------------------------------------------
// All weight conversions in one kernel + combined K/V bias.
// Regions (8-elem groups): Wq 32768 | Wk 32768 | Wv 32768 | Wo 32768 | Wg 131072
// ---------------------------------------------------------------------------
__global__ void cvt_weights_kernel(const float* __restrict__ Wq, const float* __restrict__ Wk,
                                   const float* __restrict__ Wv, const float* __restrict__ Wo,
                                   const float* __restrict__ Wg,
                                   const float* __restrict__ bk, const float* __restrict__ bv,
                                   u16* __restrict__ Wq_b, u16* __restrict__ Wkv_b,
                                   u16* __restrict__ Wo_b, u16* __restrict__ Wg_b,
                                   float* __restrict__ bkv) {
    if (blockIdx.x == 0 && threadIdx.x < 128) {
        float4 t = (threadIdx.x < 64) ? ((const float4*)bk)[threadIdx.x]
                                      : ((const float4*)bv)[threadIdx.x - 64];
        ((float4*)bkv)[threadIdx.x] = t;
    }
    int g = blockIdx.x * 256 + threadIdx.x;
    const float* src; u16* dst; size_t off;
    if (g < 32768)       { src = Wq; dst = Wq_b;          off = (size_t)g*8; }
    else if (g < 65536)  { src = Wk; dst = Wkv_b;         off = (size_t)(g-32768)*8; }
    else if (g < 98304)  { src = Wv; dst = Wkv_b + 262144; off = (size_t)(g-65536)*8; }
    else if (g < 131072) { src = Wo; dst = Wo_b;          off = (size_t)(g-98304)*8; }
    else                 { src = Wg; dst = Wg_b;          off = (size_t)(g-131072)*8; }
    float4 a0 = *(const float4*)(src + off);
    float4 a1 = *(const float4*)(src + off + 4);
    union { u16 s[8]; u32x4 v; } o;
    o.s[0] = bfbits(a0.x); o.s[1] = bfbits(a0.y); o.s[2] = bfbits(a0.z); o.s[3] = bfbits(a0.w);
    o.s[4] = bfbits(a1.x); o.s[5] = bfbits(a1.y); o.s[6] = bfbits(a1.z); o.s[7] = bfbits(a1.w);
    *(u32x4*)(dst + off) = o.v;
}

// ---------------------------------------------------------------------------
// Shared GEMM inner: 128x128 tile, BK=64, 4 waves, 4x4 frags of 16x16x32 bf16.
// F32A: A is f32 and converted to bf16 during staging.
// ---------------------------------------------------------------------------
template<int KDIM, bool F32A>
__device__ inline void gemm_accum(const void* __restrict__ Ap, const u16* __restrict__ Bw,
                                  int row0, int col0, int tid, int lane, int wm, int wn,
                                  u16 (&Asm)[128][72], u16 (&Bsm)[128][72],
                                  f32x4 (&acc)[4][4]) {
    for (int k0 = 0; k0 < KDIM; k0 += 64) {
        #pragma unroll
        for (int i = 0; i < 4; ++i) {
            int s = tid + i*256;
            int r = s >> 3, cg = (s & 7) * 8;
            u32x4 vb = *(const u32x4*)(Bw + (size_t)(col0 + r)*KDIM + k0 + cg);
            if (F32A) {
                const float* a = (const float*)Ap + (size_t)(row0 + r)*KDIM + k0 + cg;
                float4 a0 = *(const float4*)a;
                float4 a1 = *(const float4*)(a + 4);
                union { u16 s[8]; u32x4 v; } o;
                o.s[0]=bfbits(a0.x); o.s[1]=bfbits(a0.y); o.s[2]=bfbits(a0.z); o.s[3]=bfbits(a0.w);
                o.s[4]=bfbits(a1.x); o.s[5]=bfbits(a1.y); o.s[6]=bfbits(a1.z); o.s[7]=bfbits(a1.w);
                *(u32x4*)&Asm[r][cg] = o.v;
            } else {
                *(u32x4*)&Asm[r][cg] =
                    *(const u32x4*)((const u16*)Ap + (size_t)(row0 + r)*KDIM + k0 + cg);
            }
            *(u32x4*)&Bsm[r][cg] = vb;
        }
        __syncthreads();
        #pragma unroll
        for (int ks = 0; ks < 64; ks += 32) {
            bf16x8 af[4], bfr[4];
            #pragma unroll
            for (int i = 0; i < 4; ++i)
                af[i] = *(const bf16x8*)&Asm[wm + i*16 + (lane & 15)][ks + (lane >> 4)*8];
            #pragma unroll
            for (int j = 0; j < 4; ++j)
                bfr[j] = *(const bf16x8*)&Bsm[wn + j*16 + (lane & 15)][ks + (lane >> 4)*8];
            #pragma unroll
            for (int i = 0; i < 4; ++i)
                #pragma unroll
                for (int j = 0; j < 4; ++j)
                    acc[i][j] = __builtin_amdgcn_mfma_f32_16x16x32_bf16(
                        af[i], bfr[j], acc[i][j], 0, 0, 0);
        }
        __syncthreads();
    }
}

// ---------------------------------------------------------------------------
// GEMM with bias -> bf16 out (QKV projections).
// ---------------------------------------------------------------------------
template<int NOUT, int KDIM>
__global__ __launch_bounds__(256, 2)
void mfma_gemm_kernel(const u16* __restrict__ A, const u16* __restrict__ Bw,
                      const float* __restrict__ bias, u16* __restrict__ Out) {
    __shared__ u16 Asm[128][72];
    __shared__ u16 Bsm[128][72];
    int tid = threadIdx.x;
    int lane = tid & 63, wid = tid >> 6;
    int wm = (wid >> 1) * 64, wn = (wid & 1) * 64;
    int row0 = blockIdx.y * 128, col0 = blockIdx.x * 128;
    f32x4 acc[4][4] = {};
    gemm_accum<KDIM, false>(A, Bw, row0, col0, tid, lane, wm, wn, Asm, Bsm, acc);
    #pragma unroll
    for (int i = 0; i < 4; ++i) {
        #pragma unroll
        for (int j = 0; j < 4; ++j) {
            int col = col0 + wn + j*16 + (lane & 15);
            float bb = bias[col];
            #pragma unroll
            for (int r = 0; r < 4; ++r) {
                int row = row0 + wm + i*16 + (lane >> 4)*4 + r;
                Out[(size_t)row * NOUT + col] = bfbits(acc[i][j][r] + bb);
            }
        }
    }
}

// ---------------------------------------------------------------------------
// Fused gate + output projection + residual:
// out = X + sigmoid(X@Wg^T + bg) * (ctx@Wo^T + bo), f32 out.
// ---------------------------------------------------------------------------
__global__ __launch_bounds__(256, 2)
void final_fused_kernel(const float* __restrict__ query, const u16* __restrict__ Wg_b,
                        const float* __restrict__ bg,
                        const u16* __restrict__ ctxb, const u16* __restrict__ Wo_b,
                        const float* __restrict__ bo, float* __restrict__ out) {
    __shared__ u16 Asm[128][72];
    __shared__ u16 Bsm[128][72];
    int tid = threadIdx.x;
    int lane = tid & 63, wid = tid >> 6;
    int wm = (wid >> 1) * 64, wn = (wid & 1) * 64;
    int row0 = blockIdx.y * 128, col0 = blockIdx.x * 128;
    f32x4 acc_o[4][4] = {};
    f32x4 acc_g[4][4] = {};
    gemm_accum<INNER_, false>(ctxb, Wo_b, row0, col0, tid, lane, wm, wn, Asm, Bsm, acc_o);
    gemm_accum<C_, true>(query, Wg_b, row0, col0, tid, lane, wm, wn, Asm, Bsm, acc_g);
    #pragma unroll
    for (int i = 0; i < 4; ++i) {
        #pragma unroll
        for (int j = 0; j < 4; ++j) {
            int col = col0 + wn + j*16 + (lane & 15);
            float bgv = bg[col], bov = bo[col];
            #pragma unroll
            for (int r = 0; r < 4; ++r) {
                int row = row0 + wm + i*16 + (lane >> 4)*4 + r;
                size_t idx = (size_t)row * C_ + col;
                float g = 1.f / (1.f + expf(-(acc_g[i][j][r] + bgv)));
                out[idx] = query[idx] + g * (acc_o[i][j][r] + bov);
            }
        }
    }
}

// ---------------------------------------------------------------------------
// MFMA attention (validated round 3), K/V from combined KV buffer [M][512].
// ---------------------------------------------------------------------------
__device__ inline void stage_v_half(const u16* __restrict__ KV, u16* __restrict__ Vt,
                                    int b, int h, int HF, int tid) {
    #pragma unroll
    for (int i = 0; i < 9; ++i) {
        int c = tid + i*256;
        int k = c >> 3;            // 0..287
        int d0 = (c & 7) * 8;
        union { u32x4 v; u16 s[8]; } u;
        u.v = *(const u32x4*)(KV + ((size_t)(b*N_ + HF*288 + k))*512 + 256 + h*HD_ + d0);
        #pragma unroll
        for (int e = 0; e < 8; ++e)
            Vt[(d0 + e)*296 + k] = u.s[e];
    }
}

template<int HF>
__device__ inline void pv_half(const unsigned (&pk)[36][2], f32x4 (&cacc)[4],
                               const u16* __restrict__ Vt, int lane) {
    int s1 = (lane & 15) + ((lane & 16) << 1);
    int s2 = s1 + 16;
    bool hi = (lane & 32) != 0;
    #pragma unroll
    for (int t9 = 0; t9 < 9; ++t9) {
        const int t = HF*9 + t9;
        unsigned A01 = __shfl((int)pk[2*t  ][0], s1, 64);
        unsigned A23 = __shfl((int)pk[2*t  ][1], s1, 64);
        unsigned B01 = __shfl((int)pk[2*t+1][0], s1, 64);
        unsigned B23 = __shfl((int)pk[2*t+1][1], s1, 64);
        unsigned C01 = __shfl((int)pk[2*t  ][0], s2, 64);
        unsigned C23 = __shfl((int)pk[2*t  ][1], s2, 64);
        unsigned D01 = __shfl((int)pk[2*t+1][0], s2, 64);
        unsigned D23 = __shfl((int)pk[2*t+1][1], s2, 64);
        union { unsigned w[4]; bf16x8 v; } bu;
        bu.w[0] = hi ? B01 : A01;
        bu.w[1] = hi ? B23 : A23;
        bu.w[2] = hi ? D01 : C01;
        bu.w[3] = hi ? D23 : C23;
        int colb = 32*t - 288*HF + 8*(lane >> 4);
        #pragma unroll
        for (int dt = 0; dt < 4; ++dt) {
            bf16x8 a = *(const bf16x8*)&Vt[(16*dt + (lane & 15))*296 + colb];
            cacc[dt] = __builtin_amdgcn_mfma_f32_16x16x32_bf16(a, bu.v, cacc[dt], 0, 0, 0);
        }
    }
}

__global__ __launch_bounds__(256, 2)
void attn_mfma_kernel(const u16* __restrict__ Qbf, const u16* __restrict__ KV,
                      const float* __restrict__ mask,
                      float* __restrict__ attn_out, u16* __restrict__ ctxb) {
    __shared__ u16 Vt[64*296];
    __shared__ float Msk[576];
    int tid = threadIdx.x;
    int lane = tid & 63, wid = tid >> 6;
    int bh = blockIdx.y, b = bh >> 2, h = bh & 3;
    int q0 = blockIdx.x * 64;
    int g = lane >> 4;
    int qrow = q0 + wid*16 + (lane & 15);

    if (tid < 144) {
        float4 mv = *(const float4*)(mask + b*N_ + tid*4);
        *(float4*)&Msk[tid*4] = make_float4(ALPHA_*mv.x, ALPHA_*mv.y, ALPHA_*mv.z, ALPHA_*mv.w);
    }
    stage_v_half(KV, Vt, b, h, 0, tid);
    __syncthreads();

    const u16* qp = Qbf + ((size_t)(b*N_) + qrow)*INNER_ + h*HD_ + g*8;
    bf16x8 qf0 = *(const bf16x8*)qp;
    bf16x8 qf1 = *(const bf16x8*)(qp + 32);

    f32x4 acc[36];
    #pragma unroll
    for (int T = 0; T < 36; ++T) acc[T] = (f32x4){0.f, 0.f, 0.f, 0.f};

    const u16* kp = KV + ((size_t)(b*N_) + (lane & 15))*512 + h*HD_ + g*8;
    bf16x8 kb[2][2];
    kb[0][0] = *(const bf16x8*)(kp);
    kb[0][1] = *(const bf16x8*)(kp + 32);
    kb[1][0] = *(const bf16x8*)(kp + 16*512);
    kb[1][1] = *(const bf16x8*)(kp + 16*512 + 32);
    #pragma unroll
    for (int T = 0; T < 36; ++T) {
        bf16x8 n0, n1;
        if (T + 2 < 36) {
            n0 = *(const bf16x8*)(kp + (size_t)(T+2)*16*512);
            n1 = *(const bf16x8*)(kp + (size_t)(T+2)*16*512 + 32);
        }
        acc[T] = __builtin_amdgcn_mfma_f32_16x16x32_bf16(kb[T&1][0], qf0, acc[T], 0, 0, 0);
        acc[T] = __builtin_amdgcn_mfma_f32_16x16x32_bf16(kb[T&1][1], qf1, acc[T], 0, 0, 0);
        if (T + 2 < 36) { kb[T&1][0] = n0; kb[T&1][1] = n1; }
    }

    float m = -1e30f;
    #pragma unroll
    for (int T = 0; T < 36; ++T) {
        float4 mk = *(const float4*)&Msk[16*T + 4*g];
        acc[T][0] = acc[T][0]*0.125f + mk.x;
        acc[T][1] = acc[T][1]*0.125f + mk.y;
        acc[T][2] = acc[T][2]*0.125f + mk.z;
        acc[T][3] = acc[T][3]*0.125f + mk.w;
        m = fmaxf(m, fmaxf(fmaxf(acc[T][0], acc[T][1]), fmaxf(acc[T][2], acc[T][3])));
    }
    m = fmaxf(m, __shfl_xor(m, 16, 64));
    m = fmaxf(m, __shfl_xor(m, 32, 64));

    float l = 0.f;
    #pragma unroll
    for (int T = 0; T < 36; ++T) {
        acc[T][0] = expf(acc[T][0] - m);
        acc[T][1] = expf(acc[T][1] - m);
        acc[T][2] = expf(acc[T][2] - m);
        acc[T][3] = expf(acc[T][3] - m);
        l += acc[T][0] + acc[T][1] + acc[T][2] + acc[T][3];
    }
    l += __shfl_xor(l, 16, 64);
    l += __shfl_xor(l, 32, 64);
    float inv = 1.f / l;

    unsigned pk[36][2];
    float* ap = attn_out + ((size_t)bh*N_ + qrow)*N_;
    #pragma unroll
    for (int T = 0; T < 36; ++T) {
        float e0 = acc[T][0]*inv, e1 = acc[T][1]*inv;
        float e2 = acc[T][2]*inv, e3 = acc[T][3]*inv;
        *(float4*)(ap + 16*T + 4*g) = make_float4(e0, e1, e2, e3);
        pk[T][0] = pack2bf(e0, e1);
        pk[T][1] = pack2bf(e2, e3);
    }

    f32x4 cacc[4] = {};
    pv_half<0>(pk, cacc, Vt, lane);
    __syncthreads();
    stage_v_half(KV, Vt, b, h, 1, tid);
    __syncthreads();
    pv_half<1>(pk, cacc, Vt, lane);

    u16* cp = ctxb + ((size_t)(b*N_) + qrow)*INNER_ + h*HD_ + 4*g;
    #pragma unroll
    for (int dt = 0; dt < 4; ++dt) {
        ushort4 o;
        o.x = bfbits(cacc[dt][0]);
        o.y = bfbits(cacc[dt][1]);
        o.z = bfbits(cacc[dt][2]);
        o.w = bfbits(cacc[dt][3]);
        *(ushort4*)(cp + 16*dt) = o;
    }
}

// ---------------------------------------------------------------------------
extern "C" void kernel_launch(void* const* d_in, const int* in_sizes, int n_in,
                              void* d_out, int out_size, void* d_ws, size_t ws_size,
                              hipStream_t stream) {
    const float* query   = (const float*)d_in[0];
    const float* support = (const float*)d_in[1];
    const float* mask    = (const float*)d_in[2];
    const float* ln_q_w  = (const float*)d_in[3];
    const float* ln_q_b  = (const float*)d_in[4];
    const float* ln_s_w  = (const float*)d_in[5];
    const float* ln_s_b  = (const float*)d_in[6];
    const float* Wq      = (const float*)d_in[7];
    const float* bq      = (const float*)d_in[8];
    const float* Wk      = (const float*)d_in[9];
    const float* bk      = (const float*)d_in[10];
    const float* Wv      = (const float*)d_in[11];
    const float* bv      = (const float*)d_in[12];
    const float* Wo      = (const float*)d_in[13];
    const float* bo      = (const float*)d_in[14];
    const float* Wg      = (const float*)d_in[15];
    const float* bg      = (const float*)d_in[16];

    float* out      = (float*)d_out;
    float* attn_out = out + (size_t)M_ * C_;

    char* w = (char*)d_ws;
    u16* Aq    = (u16*)w;  w += (size_t)M_*C_*2;
    u16* As_   = (u16*)w;  w += (size_t)M_*C_*2;
    u16* Wq_b  = (u16*)w;  w += (size_t)INNER_*C_*2;
    u16* Wkv_b = (u16*)w;  w += (size_t)2*INNER_*C_*2;
    u16* Wo_b  = (u16*)w;  w += (size_t)C_*INNER_*2;
    u16* Wg_b  = (u16*)w;  w += (size_t)C_*C_*2;
    float* bkv = (float*)w; w += 512*4;
    u16* Qbf   = (u16*)w;  w += (size_t)M_*INNER_*2;
    u16* KVbf  = (u16*)w;  w += (size_t)M_*2*INNER_*2;
    u16* ctxb  = (u16*)w;  w += (size_t)M_*INNER_*2;

    // Fused LN (query also unused raw-write slot removed: raw conv handled in final gemm)
    ln_fused_kernel<0><<<dim3(M_/4), dim3(256), 0, stream>>>(query,   ln_q_w, ln_q_b, Aq,  nullptr);
    ln_fused_kernel<0><<<dim3(M_/4), dim3(256), 0, stream>>>(support, ln_s_w, ln_s_b, As_, nullptr);

    // All weight conversions + combined kv bias
    cvt_weights_kernel<<<dim3(1024), dim3(256), 0, stream>>>(
        Wq, Wk, Wv, Wo, Wg, bk, bv, Wq_b, Wkv_b, Wo_b, Wg_b, bkv);

    // Q projection (N=256), KV projection (N=512, fused)
    mfma_gemm_kernel<INNER_, C_><<<dim3(INNER_/128, M_/128), dim3(256), 0, stream>>>(
        Aq, Wq_b, bq, Qbf);
    mfma_gemm_kernel<2*INNER_, C_><<<dim3(2*INNER_/128, M_/128), dim3(256), 0, stream>>>(
        As_, Wkv_b, bkv, KVbf);

    // attention
    attn_mfma_kernel<<<dim3(N_/64, B_*H_), dim3(256), 0, stream>>>(
        Qbf, KVbf, mask, attn_out, ctxb);

    // fused gate + output proj + residual
    final_fused_kernel<<<dim3(C_/128, M_/128), dim3(256), 0, stream>>>(
        query, Wg_b, bg, ctxb, Wo_b, bo, out);
}

// Round 5
// 350.945 us; speedup vs baseline: 7.1857x; 1.0498x over previous
//
#include <hip/hip_runtime.h>
#include <hip/hip_bf16.h>
#include <math.h>

#define B_ 32
#define N_ 576
#define C_ 1024
#define INNER_ 256
#define H_ 4
#define HD_ 64
#define M_ (B_*N_)           // 18432
#define ALPHA_ 5.0f
#define EPS_ 1e-5f

typedef __attribute__((ext_vector_type(8))) short bf16x8;
typedef __attribute__((ext_vector_type(4))) float f32x4;
typedef __attribute__((ext_vector_type(4))) unsigned int u32x4;
typedef unsigned short u16;

__device__ inline u16 bfbits(float x) {
    union { __hip_bfloat16 h; u16 u; } c; c.h = __float2bfloat16(x); return c.u;
}
__device__ inline unsigned pack2bf(float a, float b) {
    return (unsigned)bfbits(a) | ((unsigned)bfbits(b) << 16);
}

// XCD row-clustering swizzle: all GX column-blocks of a row-band map to one
// XCD so the A-tile stays in that XCD's L2. Bijective when GY % 8 == 0.
template<int GX, int GY>
__device__ inline void xcd_remap(int& col, int& row) {
    int f = blockIdx.y * GX + blockIdx.x;
    int xcd = f & 7;
    int slot = f >> 3;
    col = slot % GX;
    row = xcd * (GY >> 3) + slot / GX;
}

// ---------------------------------------------------------------------------
// Fused LayerNorm: one wave per row; optionally also writes raw input as bf16.
// ---------------------------------------------------------------------------
template<int WRITE_RAW>
__global__ void ln_fused_kernel(const float* __restrict__ X, const float* __restrict__ w,
                                const float* __restrict__ b, u16* __restrict__ outln,
                                u16* __restrict__ outraw) {
    int row = blockIdx.x * 4 + (threadIdx.x >> 6);
    int lane = threadIdx.x & 63;
    const float* xp = X + (size_t)row * C_;
    float4 v[4];
    #pragma unroll
    for (int j = 0; j < 4; ++j) v[j] = *(const float4*)(xp + lane*4 + j*256);
    float s = 0.f, s2 = 0.f;
    #pragma unroll
    for (int j = 0; j < 4; ++j) {
        s  += v[j].x + v[j].y + v[j].z + v[j].w;
        s2 += v[j].x*v[j].x + v[j].y*v[j].y + v[j].z*v[j].z + v[j].w*v[j].w;
    }
    #pragma unroll
    for (int m = 32; m; m >>= 1) {
        s  += __shfl_xor(s,  m, 64);
        s2 += __shfl_xor(s2, m, 64);
    }
    float mean = s * (1.f/C_);
    float rs = rsqrtf(s2 * (1.f/C_) - mean*mean + EPS_);
    #pragma unroll
    for (int j = 0; j < 4; ++j) {
        int k = lane*4 + j*256;
        float4 wv = *(const float4*)(w + k);
        float4 bv = *(const float4*)(b + k);
        ushort4 o;
        o.x = bfbits((v[j].x - mean)*rs*wv.x + bv.x);
        o.y = bfbits((v[j].y - mean)*rs*wv.y + bv.y);
        o.z = bfbits((v[j].z - mean)*rs*wv.z + bv.z);
        o.w = bfbits((v[j].w - mean)*rs*wv.w + bv.w);
        *(ushort4*)(outln + (size_t)row*C_ + k) = o;
        if (WRITE_RAW) {
            ushort4 r4;
            r4.x = bfbits(v[j].x); r4.y = bfbits(v[j].y);
            r4.z = bfbits(v[j].z); r4.w = bfbits(v[j].w);
            *(ushort4*)(outraw + (size_t)row*C_ + k) = r4;
        }
    }
}

// ---------------------------------------------------------------------------
// All weight conversions in one kernel + combined K/V bias.
// ---------------------------------------------------------------------------
__global__ void cvt_weights_kernel(const float* __restrict__ Wq, const float* __restrict__ Wk,
                                   const float* __restrict__ Wv, const float* __restrict__ Wo,
                                   const float* __restrict__ Wg,
                                   const float* __restrict__ bk, const float* __restrict__ bv,
                                   u16* __restrict__ Wq_b, u16* __restrict__ Wkv_b,
                                   u16* __restrict__ Wo_b, u16* __restrict__ Wg_b,
                                   float* __restrict__ bkv) {
    if (blockIdx.x == 0 && threadIdx.x < 128) {
        float4 t = (threadIdx.x < 64) ? ((const float4*)bk)[threadIdx.x]
                                      : ((const float4*)bv)[threadIdx.x - 64];
        ((float4*)bkv)[threadIdx.x] = t;
    }
    int g = blockIdx.x * 256 + threadIdx.x;
    const float* src; u16* dst; size_t off;
    if (g < 32768)       { src = Wq; dst = Wq_b;          off = (size_t)g*8; }
    else if (g < 65536)  { src = Wk; dst = Wkv_b;         off = (size_t)(g-32768)*8; }
    else if (g < 98304)  { src = Wv; dst = Wkv_b + 262144; off = (size_t)(g-65536)*8; }
    else if (g < 131072) { src = Wo; dst = Wo_b;          off = (size_t)(g-98304)*8; }
    else                 { src = Wg; dst = Wg_b;          off = (size_t)(g-131072)*8; }
    float4 a0 = *(const float4*)(src + off);
    float4 a1 = *(const float4*)(src + off + 4);
    union { u16 s[8]; u32x4 v; } o;
    o.s[0] = bfbits(a0.x); o.s[1] = bfbits(a0.y); o.s[2] = bfbits(a0.z); o.s[3] = bfbits(a0.w);
    o.s[4] = bfbits(a1.x); o.s[5] = bfbits(a1.y); o.s[6] = bfbits(a1.z); o.s[7] = bfbits(a1.w);
    *(u32x4*)(dst + off) = o.v;
}

// ---------------------------------------------------------------------------
// Shared GEMM inner: 128x128 tile, BK=64, 4 waves, 4x4 frags of 16x16x32 bf16.
// ---------------------------------------------------------------------------
template<int KDIM>
__device__ inline void gemm_accum(const u16* __restrict__ Ap, const u16* __restrict__ Bw,
                                  int row0, int col0, int tid, int lane, int wm, int wn,
                                  u16 (&Asm)[128][72], u16 (&Bsm)[128][72],
                                  f32x4 (&acc)[4][4]) {
    for (int k0 = 0; k0 < KDIM; k0 += 64) {
        #pragma unroll
        for (int i = 0; i < 4; ++i) {
            int s = tid + i*256;
            int r = s >> 3, cg = (s & 7) * 8;
            *(u32x4*)&Asm[r][cg] = *(const u32x4*)(Ap + (size_t)(row0 + r)*KDIM + k0 + cg);
            *(u32x4*)&Bsm[r][cg] = *(const u32x4*)(Bw + (size_t)(col0 + r)*KDIM + k0 + cg);
        }
        __syncthreads();
        #pragma unroll
        for (int ks = 0; ks < 64; ks += 32) {
            bf16x8 af[4], bfr[4];
            #pragma unroll
            for (int i = 0; i < 4; ++i)
                af[i] = *(const bf16x8*)&Asm[wm + i*16 + (lane & 15)][ks + (lane >> 4)*8];
            #pragma unroll
            for (int j = 0; j < 4; ++j)
                bfr[j] = *(const bf16x8*)&Bsm[wn + j*16 + (lane & 15)][ks + (lane >> 4)*8];
            #pragma unroll
            for (int i = 0; i < 4; ++i)
                #pragma unroll
                for (int j = 0; j < 4; ++j)
                    acc[i][j] = __builtin_amdgcn_mfma_f32_16x16x32_bf16(
                        af[i], bfr[j], acc[i][j], 0, 0, 0);
        }
        __syncthreads();
    }
}

// ---------------------------------------------------------------------------
// GEMM with bias -> bf16 out (QKV projections). GX/GY = grid dims for swizzle.
// ---------------------------------------------------------------------------
template<int NOUT, int KDIM, int GX, int GY>
__global__ __launch_bounds__(256, 2)
void mfma_gemm_kernel(const u16* __restrict__ A, const u16* __restrict__ Bw,
                      const float* __restrict__ bias, u16* __restrict__ Out) {
    __shared__ u16 Asm[128][72];
    __shared__ u16 Bsm[128][72];
    int tid = threadIdx.x;
    int lane = tid & 63, wid = tid >> 6;
    int wm = (wid >> 1) * 64, wn = (wid & 1) * 64;
    int bc, br;
    xcd_remap<GX, GY>(bc, br);
    int row0 = br * 128, col0 = bc * 128;
    f32x4 acc[4][4] = {};
    gemm_accum<KDIM>(A, Bw, row0, col0, tid, lane, wm, wn, Asm, Bsm, acc);
    #pragma unroll
    for (int i = 0; i < 4; ++i) {
        #pragma unroll
        for (int j = 0; j < 4; ++j) {
            int col = col0 + wn + j*16 + (lane & 15);
            float bb = bias[col];
            #pragma unroll
            for (int r = 0; r < 4; ++r) {
                int row = row0 + wm + i*16 + (lane >> 4)*4 + r;
                Out[(size_t)row * NOUT + col] = bfbits(acc[i][j][r] + bb);
            }
        }
    }
}

// ---------------------------------------------------------------------------
// Fused gate + output projection + residual:
// out = X + sigmoid(Xq@Wg^T + bg) * (ctx@Wo^T + bo), f32 out.
// ---------------------------------------------------------------------------
__global__ __launch_bounds__(256, 2)
void final_fused_kernel(const float* __restrict__ query, const u16* __restrict__ Xq,
                        const u16* __restrict__ Wg_b, const float* __restrict__ bg,
                        const u16* __restrict__ ctxb, const u16* __restrict__ Wo_b,
                        const float* __restrict__ bo, float* __restrict__ out) {
    __shared__ u16 Asm[128][72];
    __shared__ u16 Bsm[128][72];
    int tid = threadIdx.x;
    int lane = tid & 63, wid = tid >> 6;
    int wm = (wid >> 1) * 64, wn = (wid & 1) * 64;
    int bc, br;
    xcd_remap<8, 144>(bc, br);
    int row0 = br * 128, col0 = bc * 128;
    f32x4 acc_o[4][4] = {};
    f32x4 acc_g[4][4] = {};
    gemm_accum<INNER_>(ctxb, Wo_b, row0, col0, tid, lane, wm, wn, Asm, Bsm, acc_o);
    gemm_accum<C_>(Xq, Wg_b, row0, col0, tid, lane, wm, wn, Asm, Bsm, acc_g);
    #pragma unroll
    for (int i = 0; i < 4; ++i) {
        #pragma unroll
        for (int j = 0; j < 4; ++j) {
            int col = col0 + wn + j*16 + (lane & 15);
            float bgv = bg[col], bov = bo[col];
            #pragma unroll
            for (int r = 0; r < 4; ++r) {
                int row = row0 + wm + i*16 + (lane >> 4)*4 + r;
                size_t idx = (size_t)row * C_ + col;
                float g = 1.f / (1.f + expf(-(acc_g[i][j][r] + bgv)));
                out[idx] = query[idx] + g * (acc_o[i][j][r] + bov);
            }
        }
    }
}

// ---------------------------------------------------------------------------
// MFMA attention, K/V from combined KV buffer [M][512].
// ---------------------------------------------------------------------------
__device__ inline void stage_v_half(const u16* __restrict__ KV, u16* __restrict__ Vt,
                                    int b, int h, int HF, int tid) {
    #pragma unroll
    for (int i = 0; i < 9; ++i) {
        int c = tid + i*256;
        int k = c >> 3;            // 0..287
        int d0 = (c & 7) * 8;
        union { u32x4 v; u16 s[8]; } u;
        u.v = *(const u32x4*)(KV + ((size_t)(b*N_ + HF*288 + k))*512 + 256 + h*HD_ + d0);
        #pragma unroll
        for (int e = 0; e < 8; ++e)
            Vt[(d0 + e)*296 + k] = u.s[e];
    }
}

template<int HF>
__device__ inline void pv_half(const unsigned (&pk)[36][2], f32x4 (&cacc)[4],
                               const u16* __restrict__ Vt, int lane) {
    int s1 = (lane & 15) + ((lane & 16) << 1);
    int s2 = s1 + 16;
    bool hi = (lane & 32) != 0;
    #pragma unroll
    for (int t9 = 0; t9 < 9; ++t9) {
        const int t = HF*9 + t9;
        unsigned A01 = __shfl((int)pk[2*t  ][0], s1, 64);
        unsigned A23 = __shfl((int)pk[2*t  ][1], s1, 64);
        unsigned B01 = __shfl((int)pk[2*t+1][0], s1, 64);
        unsigned B23 = __shfl((int)pk[2*t+1][1], s1, 64);
        unsigned C01 = __shfl((int)pk[2*t  ][0], s2, 64);
        unsigned C23 = __shfl((int)pk[2*t  ][1], s2, 64);
        unsigned D01 = __shfl((int)pk[2*t+1][0], s2, 64);
        unsigned D23 = __shfl((int)pk[2*t+1][1], s2, 64);
        union { unsigned w[4]; bf16x8 v; } bu;
        bu.w[0] = hi ? B01 : A01;
        bu.w[1] = hi ? B23 : A23;
        bu.w[2] = hi ? D01 : C01;
        bu.w[3] = hi ? D23 : C23;
        int colb = 32*t - 288*HF + 8*(lane >> 4);
        #pragma unroll
        for (int dt = 0; dt < 4; ++dt) {
            bf16x8 a = *(const bf16x8*)&Vt[(16*dt + (lane & 15))*296 + colb];
            cacc[dt] = __builtin_amdgcn_mfma_f32_16x16x32_bf16(a, bu.v, cacc[dt], 0, 0, 0);
        }
    }
}

__global__ __launch_bounds__(256, 2)
void attn_mfma_kernel(const u16* __restrict__ Qbf, const u16* __restrict__ KV,
                      const float* __restrict__ mask,
                      float* __restrict__ attn_out, u16* __restrict__ ctxb) {
    __shared__ u16 Vt[64*296];
    __shared__ float Msk[576];
    int tid = threadIdx.x;
    int lane = tid & 63, wid = tid >> 6;
    int qb, bh;
    xcd_remap<9, 128>(qb, bh);           // cluster all q-blocks of a (b,h) on one XCD
    int b = bh >> 2, h = bh & 3;
    int q0 = qb * 64;
    int g = lane >> 4;
    int qrow = q0 + wid*16 + (lane & 15);

    if (tid < 144) {
        float4 mv = *(const float4*)(mask + b*N_ + tid*4);
        *(float4*)&Msk[tid*4] = make_float4(ALPHA_*mv.x, ALPHA_*mv.y, ALPHA_*mv.z, ALPHA_*mv.w);
    }
    stage_v_half(KV, Vt, b, h, 0, tid);
    __syncthreads();

    const u16* qp = Qbf + ((size_t)(b*N_) + qrow)*INNER_ + h*HD_ + g*8;
    bf16x8 qf0 = *(const bf16x8*)qp;
    bf16x8 qf1 = *(const bf16x8*)(qp + 32);

    f32x4 acc[36];
    #pragma unroll
    for (int T = 0; T < 36; ++T) acc[T] = (f32x4){0.f, 0.f, 0.f, 0.f};

    const u16* kp = KV + ((size_t)(b*N_) + (lane & 15))*512 + h*HD_ + g*8;
    bf16x8 kb[2][2];
    kb[0][0] = *(const bf16x8*)(kp);
    kb[0][1] = *(const bf16x8*)(kp + 32);
    kb[1][0] = *(const bf16x8*)(kp + 16*512);
    kb[1][1] = *(const bf16x8*)(kp + 16*512 + 32);
    #pragma unroll
    for (int T = 0; T < 36; ++T) {
        bf16x8 n0, n1;
        if (T + 2 < 36) {
            n0 = *(const bf16x8*)(kp + (size_t)(T+2)*16*512);
            n1 = *(const bf16x8*)(kp + (size_t)(T+2)*16*512 + 32);
        }
        acc[T] = __builtin_amdgcn_mfma_f32_16x16x32_bf16(kb[T&1][0], qf0, acc[T], 0, 0, 0);
        acc[T] = __builtin_amdgcn_mfma_f32_16x16x32_bf16(kb[T&1][1], qf1, acc[T], 0, 0, 0);
        if (T + 2 < 36) { kb[T&1][0] = n0; kb[T&1][1] = n1; }
    }

    float m = -1e30f;
    #pragma unroll
    for (int T = 0; T < 36; ++T) {
        float4 mk = *(const float4*)&Msk[16*T + 4*g];
        acc[T][0] = acc[T][0]*0.125f + mk.x;
        acc[T][1] = acc[T][1]*0.125f + mk.y;
        acc[T][2] = acc[T][2]*0.125f + mk.z;
        acc[T][3] = acc[T][3]*0.125f + mk.w;
        m = fmaxf(m, fmaxf(fmaxf(acc[T][0], acc[T][1]), fmaxf(acc[T][2], acc[T][3])));
    }
    m = fmaxf(m, __shfl_xor(m, 16, 64));
    m = fmaxf(m, __shfl_xor(m, 32, 64));

    float l = 0.f;
    #pragma unroll
    for (int T = 0; T < 36; ++T) {
        acc[T][0] = expf(acc[T][0] - m);
        acc[T][1] = expf(acc[T][1] - m);
        acc[T][2] = expf(acc[T][2] - m);
        acc[T][3] = expf(acc[T][3] - m);
        l += acc[T][0] + acc[T][1] + acc[T][2] + acc[T][3];
    }
    l += __shfl_xor(l, 16, 64);
    l += __shfl_xor(l, 32, 64);
    float inv = 1.f / l;

    unsigned pk[36][2];
    float* ap = attn_out + ((size_t)bh*N_ + qrow)*N_;
    #pragma unroll
    for (int T = 0; T < 36; ++T) {
        float e0 = acc[T][0]*inv, e1 = acc[T][1]*inv;
        float e2 = acc[T][2]*inv, e3 = acc[T][3]*inv;
        *(float4*)(ap + 16*T + 4*g) = make_float4(e0, e1, e2, e3);
        pk[T][0] = pack2bf(e0, e1);
        pk[T][1] = pack2bf(e2, e3);
    }

    f32x4 cacc[4] = {};
    pv_half<0>(pk, cacc, Vt, lane);
    __syncthreads();
    stage_v_half(KV, Vt, b, h, 1, tid);
    __syncthreads();
    pv_half<1>(pk, cacc, Vt, lane);

    u16* cp = ctxb + ((size_t)(b*N_) + qrow)*INNER_ + h*HD_ + 4*g;
    #pragma unroll
    for (int dt = 0; dt < 4; ++dt) {
        ushort4 o;
        o.x = bfbits(cacc[dt][0]);
        o.y = bfbits(cacc[dt][1]);
        o.z = bfbits(cacc[dt][2]);
        o.w = bfbits(cacc[dt][3]);
        *(ushort4*)(cp + 16*dt) = o;
    }
}

// ---------------------------------------------------------------------------
extern "C" void kernel_launch(void* const* d_in, const int* in_sizes, int n_in,
                              void* d_out, int out_size, void* d_ws, size_t ws_size,
                              hipStream_t stream) {
    const float* query   = (const float*)d_in[0];
    const float* support = (const float*)d_in[1];
    const float* mask    = (const float*)d_in[2];
    const float* ln_q_w  = (const float*)d_in[3];
    const float* ln_q_b  = (const float*)d_in[4];
    const float* ln_s_w  = (const float*)d_in[5];
    const float* ln_s_b  = (const float*)d_in[6];
    const float* Wq      = (const float*)d_in[7];
    const float* bq      = (const float*)d_in[8];
    const float* Wk      = (const float*)d_in[9];
    const float* bk      = (const float*)d_in[10];
    const float* Wv      = (const float*)d_in[11];
    const float* bv      = (const float*)d_in[12];
    const float* Wo      = (const float*)d_in[13];
    const float* bo      = (const float*)d_in[14];
    const float* Wg      = (const float*)d_in[15];
    const float* bg      = (const float*)d_in[16];

    float* out      = (float*)d_out;
    float* attn_out = out + (size_t)M_ * C_;

    char* w = (char*)d_ws;
    u16* Aq    = (u16*)w;  w += (size_t)M_*C_*2;
    u16* As_   = (u16*)w;  w += (size_t)M_*C_*2;
    u16* Xq    = (u16*)w;  w += (size_t)M_*C_*2;
    u16* Wq_b  = (u16*)w;  w += (size_t)INNER_*C_*2;
    u16* Wkv_b = (u16*)w;  w += (size_t)2*INNER_*C_*2;
    u16* Wo_b  = (u16*)w;  w += (size_t)C_*INNER_*2;
    u16* Wg_b  = (u16*)w;  w += (size_t)C_*C_*2;
    float* bkv = (float*)w; w += 512*4;
    u16* Qbf   = (u16*)w;  w += (size_t)M_*INNER_*2;
    u16* KVbf  = (u16*)w;  w += (size_t)M_*2*INNER_*2;
    u16* ctxb  = (u16*)w;  w += (size_t)M_*INNER_*2;

    // Fused LN; query pass also emits raw bf16 (Xq) for the gate GEMM
    ln_fused_kernel<1><<<dim3(M_/4), dim3(256), 0, stream>>>(query,   ln_q_w, ln_q_b, Aq,  Xq);
    ln_fused_kernel<0><<<dim3(M_/4), dim3(256), 0, stream>>>(support, ln_s_w, ln_s_b, As_, nullptr);

    // All weight conversions + combined kv bias
    cvt_weights_kernel<<<dim3(1024), dim3(256), 0, stream>>>(
        Wq, Wk, Wv, Wo, Wg, bk, bv, Wq_b, Wkv_b, Wo_b, Wg_b, bkv);

    // Q projection (N=256), KV projection (N=512, fused)
    mfma_gemm_kernel<INNER_, C_, 2, 144><<<dim3(2, 144), dim3(256), 0, stream>>>(
        Aq, Wq_b, bq, Qbf);
    mfma_gemm_kernel<2*INNER_, C_, 4, 144><<<dim3(4, 144), dim3(256), 0, stream>>>(
        As_, Wkv_b, bkv, KVbf);

    // attention
    attn_mfma_kernel<<<dim3(N_/64, B_*H_), dim3(256), 0, stream>>>(
        Qbf, KVbf, mask, attn_out, ctxb);

    // fused gate + output proj + residual
    final_fused_kernel<<<dim3(8, 144), dim3(256), 0, stream>>>(
        query, Xq, Wg_b, bg, ctxb, Wo_b, bo, out);
}

// Round 6
// 307.918 us; speedup vs baseline: 8.1898x; 1.1397x over previous
//
#include <hip/hip_runtime.h>
#include <hip/hip_bf16.h>
#include <math.h>

#define B_ 32
#define N_ 576
#define C_ 1024
#define INNER_ 256
#define H_ 4
#define HD_ 64
#define M_ (B_*N_)           // 18432
#define ALPHA_ 5.0f
#define EPS_ 1e-5f

typedef __attribute__((ext_vector_type(8))) short bf16x8;
typedef __attribute__((ext_vector_type(4))) float f32x4;
typedef __attribute__((ext_vector_type(4))) unsigned int u32x4;
typedef unsigned short u16;

__device__ inline u16 bfbits(float x) {
    union { __hip_bfloat16 h; u16 u; } c; c.h = __float2bfloat16(x); return c.u;
}
__device__ inline unsigned pack2bf(float a, float b) {
    return (unsigned)bfbits(a) | ((unsigned)bfbits(b) << 16);
}

// XCD row-clustering swizzle: all GX column-blocks of a row-band map to one
// XCD so the A-tile stays in that XCD's L2. Bijective when GX*GY % 8 == 0.
template<int GX, int GY>
__device__ inline void xcd_remap(int& col, int& row) {
    int f = blockIdx.y * GX + blockIdx.x;
    int xcd = f & 7;
    int slot = f >> 3;
    col = slot % GX;
    row = xcd * (GY >> 3) + slot / GX;
}

// ---------------------------------------------------------------------------
// Fused LayerNorm for both tensors in one launch (blockIdx.y selects tensor).
// One wave per row: stats via shfl butterfly, apply + bf16 write in one pass.
// ---------------------------------------------------------------------------
__global__ void ln_fused2_kernel(const float* __restrict__ Xq, const float* __restrict__ Xs,
                                 const float* __restrict__ wq, const float* __restrict__ bq,
                                 const float* __restrict__ ws, const float* __restrict__ bs,
                                 u16* __restrict__ outq, u16* __restrict__ outs) {
    const float* X; const float* w; const float* b; u16* o;
    if (blockIdx.y == 0) { X = Xq; w = wq; b = bq; o = outq; }
    else                 { X = Xs; w = ws; b = bs; o = outs; }
    int row = blockIdx.x * 4 + (threadIdx.x >> 6);
    int lane = threadIdx.x & 63;
    const float* xp = X + (size_t)row * C_;
    float4 v[4];
    #pragma unroll
    for (int j = 0; j < 4; ++j) v[j] = *(const float4*)(xp + lane*4 + j*256);
    float s = 0.f, s2 = 0.f;
    #pragma unroll
    for (int j = 0; j < 4; ++j) {
        s  += v[j].x + v[j].y + v[j].z + v[j].w;
        s2 += v[j].x*v[j].x + v[j].y*v[j].y + v[j].z*v[j].z + v[j].w*v[j].w;
    }
    #pragma unroll
    for (int m = 32; m; m >>= 1) {
        s  += __shfl_xor(s,  m, 64);
        s2 += __shfl_xor(s2, m, 64);
    }
    float mean = s * (1.f/C_);
    float rs = rsqrtf(s2 * (1.f/C_) - mean*mean + EPS_);
    #pragma unroll
    for (int j = 0; j < 4; ++j) {
        int k = lane*4 + j*256;
        float4 wv = *(const float4*)(w + k);
        float4 bv = *(const float4*)(b + k);
        ushort4 ov;
        ov.x = bfbits((v[j].x - mean)*rs*wv.x + bv.x);
        ov.y = bfbits((v[j].y - mean)*rs*wv.y + bv.y);
        ov.z = bfbits((v[j].z - mean)*rs*wv.z + bv.z);
        ov.w = bfbits((v[j].w - mean)*rs*wv.w + bv.w);
        *(ushort4*)(o + (size_t)row*C_ + k) = ov;
    }
}

// ---------------------------------------------------------------------------
// All weight conversions in one kernel + combined K/V bias.
// ---------------------------------------------------------------------------
__global__ void cvt_weights_kernel(const float* __restrict__ Wq, const float* __restrict__ Wk,
                                   const float* __restrict__ Wv, const float* __restrict__ Wo,
                                   const float* __restrict__ Wg,
                                   const float* __restrict__ bk, const float* __restrict__ bv,
                                   u16* __restrict__ Wq_b, u16* __restrict__ Wkv_b,
                                   u16* __restrict__ Wo_b, u16* __restrict__ Wg_b,
                                   float* __restrict__ bkv) {
    if (blockIdx.x == 0 && threadIdx.x < 128) {
        float4 t = (threadIdx.x < 64) ? ((const float4*)bk)[threadIdx.x]
                                      : ((const float4*)bv)[threadIdx.x - 64];
        ((float4*)bkv)[threadIdx.x] = t;
    }
    int g = blockIdx.x * 256 + threadIdx.x;
    const float* src; u16* dst; size_t off;
    if (g < 32768)       { src = Wq; dst = Wq_b;          off = (size_t)g*8; }
    else if (g < 65536)  { src = Wk; dst = Wkv_b;         off = (size_t)(g-32768)*8; }
    else if (g < 98304)  { src = Wv; dst = Wkv_b + 262144; off = (size_t)(g-65536)*8; }
    else if (g < 131072) { src = Wo; dst = Wo_b;          off = (size_t)(g-98304)*8; }
    else                 { src = Wg; dst = Wg_b;          off = (size_t)(g-131072)*8; }
    float4 a0 = *(const float4*)(src + off);
    float4 a1 = *(const float4*)(src + off + 4);
    union { u16 s[8]; u32x4 v; } o;
    o.s[0] = bfbits(a0.x); o.s[1] = bfbits(a0.y); o.s[2] = bfbits(a0.z); o.s[3] = bfbits(a0.w);
    o.s[4] = bfbits(a1.x); o.s[5] = bfbits(a1.y); o.s[6] = bfbits(a1.z); o.s[7] = bfbits(a1.w);
    *(u32x4*)(dst + off) = o.v;
}

// ---------------------------------------------------------------------------
// Shared GEMM inner: 128x128 tile, BK=64, 4 waves, 4x4 frags of 16x16x32 bf16.
// F32A: A is f32, converted to bf16 during staging (same rounding as precvt).
// ---------------------------------------------------------------------------
template<int KDIM, bool F32A>
__device__ inline void gemm_accum(const void* __restrict__ Ap, const u16* __restrict__ Bw,
                                  int row0, int col0, int tid, int lane, int wm, int wn,
                                  u16 (&Asm)[128][72], u16 (&Bsm)[128][72],
                                  f32x4 (&acc)[4][4]) {
    for (int k0 = 0; k0 < KDIM; k0 += 64) {
        #pragma unroll
        for (int i = 0; i < 4; ++i) {
            int s = tid + i*256;
            int r = s >> 3, cg = (s & 7) * 8;
            u32x4 vb = *(const u32x4*)(Bw + (size_t)(col0 + r)*KDIM + k0 + cg);
            if (F32A) {
                const float* a = (const float*)Ap + (size_t)(row0 + r)*KDIM + k0 + cg;
                float4 a0 = *(const float4*)a;
                float4 a1 = *(const float4*)(a + 4);
                union { u16 s[8]; u32x4 v; } o;
                o.s[0]=bfbits(a0.x); o.s[1]=bfbits(a0.y); o.s[2]=bfbits(a0.z); o.s[3]=bfbits(a0.w);
                o.s[4]=bfbits(a1.x); o.s[5]=bfbits(a1.y); o.s[6]=bfbits(a1.z); o.s[7]=bfbits(a1.w);
                *(u32x4*)&Asm[r][cg] = o.v;
            } else {
                *(u32x4*)&Asm[r][cg] =
                    *(const u32x4*)((const u16*)Ap + (size_t)(row0 + r)*KDIM + k0 + cg);
            }
            *(u32x4*)&Bsm[r][cg] = vb;
        }
        __syncthreads();
        #pragma unroll
        for (int ks = 0; ks < 64; ks += 32) {
            bf16x8 af[4], bfr[4];
            #pragma unroll
            for (int i = 0; i < 4; ++i)
                af[i] = *(const bf16x8*)&Asm[wm + i*16 + (lane & 15)][ks + (lane >> 4)*8];
            #pragma unroll
            for (int j = 0; j < 4; ++j)
                bfr[j] = *(const bf16x8*)&Bsm[wn + j*16 + (lane & 15)][ks + (lane >> 4)*8];
            #pragma unroll
            for (int i = 0; i < 4; ++i)
                #pragma unroll
                for (int j = 0; j < 4; ++j)
                    acc[i][j] = __builtin_amdgcn_mfma_f32_16x16x32_bf16(
                        af[i], bfr[j], acc[i][j], 0, 0, 0);
        }
        __syncthreads();
    }
}

// ---------------------------------------------------------------------------
// Q + KV projections in one launch. grid (6,144) swizzled: col-blocks 0-1 = Q
// (Aq x Wq -> Qbf[M][256]), 2-5 = KV (As x Wkv -> KVbf[M][512]).
// ---------------------------------------------------------------------------
__global__ __launch_bounds__(256, 2)
void qkv_gemm_kernel(const u16* __restrict__ Aq, const u16* __restrict__ As,
                     const u16* __restrict__ Wq_b, const u16* __restrict__ Wkv_b,
                     const float* __restrict__ bq, const float* __restrict__ bkv,
                     u16* __restrict__ Qbf, u16* __restrict__ KVbf) {
    __shared__ u16 Asm[128][72];
    __shared__ u16 Bsm[128][72];
    int tid = threadIdx.x;
    int lane = tid & 63, wid = tid >> 6;
    int wm = (wid >> 1) * 64, wn = (wid & 1) * 64;
    int bc, br;
    xcd_remap<6, 144>(bc, br);
    int row0 = br * 128;
    bool isQ = (bc < 2);
    int col0 = (isQ ? bc : bc - 2) * 128;
    const u16* A  = isQ ? Aq   : As;
    const u16* Bw = isQ ? Wq_b : Wkv_b;
    const float* bias = isQ ? bq : bkv;
    u16* Out = isQ ? Qbf : KVbf;
    const int NOUT = isQ ? INNER_ : 2*INNER_;
    f32x4 acc[4][4] = {};
    gemm_accum<C_, false>(A, Bw, row0, col0, tid, lane, wm, wn, Asm, Bsm, acc);
    #pragma unroll
    for (int i = 0; i < 4; ++i) {
        #pragma unroll
        for (int j = 0; j < 4; ++j) {
            int col = col0 + wn + j*16 + (lane & 15);
            float bb = bias[col];
            #pragma unroll
            for (int r = 0; r < 4; ++r) {
                int row = row0 + wm + i*16 + (lane >> 4)*4 + r;
                Out[(size_t)row * NOUT + col] = bfbits(acc[i][j][r] + bb);
            }
        }
    }
}

// ---------------------------------------------------------------------------
// Fused gate + output projection + residual:
// out = X + sigmoid(X@Wg^T + bg) * (ctx@Wo^T + bo), f32 out.
// Gate A-operand staged from f32 query on the fly (L2-resident per row-band).
// ---------------------------------------------------------------------------
__global__ __launch_bounds__(256, 2)
void final_fused_kernel(const float* __restrict__ query,
                        const u16* __restrict__ Wg_b, const float* __restrict__ bg,
                        const u16* __restrict__ ctxb, const u16* __restrict__ Wo_b,
                        const float* __restrict__ bo, float* __restrict__ out) {
    __shared__ u16 Asm[128][72];
    __shared__ u16 Bsm[128][72];
    int tid = threadIdx.x;
    int lane = tid & 63, wid = tid >> 6;
    int wm = (wid >> 1) * 64, wn = (wid & 1) * 64;
    int bc, br;
    xcd_remap<8, 144>(bc, br);
    int row0 = br * 128, col0 = bc * 128;
    f32x4 acc_o[4][4] = {};
    f32x4 acc_g[4][4] = {};
    gemm_accum<INNER_, false>(ctxb, Wo_b, row0, col0, tid, lane, wm, wn, Asm, Bsm, acc_o);
    gemm_accum<C_, true>(query, Wg_b, row0, col0, tid, lane, wm, wn, Asm, Bsm, acc_g);
    #pragma unroll
    for (int i = 0; i < 4; ++i) {
        #pragma unroll
        for (int j = 0; j < 4; ++j) {
            int col = col0 + wn + j*16 + (lane & 15);
            float bgv = bg[col], bov = bo[col];
            #pragma unroll
            for (int r = 0; r < 4; ++r) {
                int row = row0 + wm + i*16 + (lane >> 4)*4 + r;
                size_t idx = (size_t)row * C_ + col;
                float g = 1.f / (1.f + expf(-(acc_g[i][j][r] + bgv)));
                __builtin_nontemporal_store(query[idx] + g * (acc_o[i][j][r] + bov), &out[idx]);
            }
        }
    }
}

// ---------------------------------------------------------------------------
// MFMA attention, K/V from combined KV buffer [M][512].
// ---------------------------------------------------------------------------
__device__ inline void stage_v_half(const u16* __restrict__ KV, u16* __restrict__ Vt,
                                    int b, int h, int HF, int tid) {
    #pragma unroll
    for (int i = 0; i < 9; ++i) {
        int c = tid + i*256;
        int k = c >> 3;            // 0..287
        int d0 = (c & 7) * 8;
        union { u32x4 v; u16 s[8]; } u;
        u.v = *(const u32x4*)(KV + ((size_t)(b*N_ + HF*288 + k))*512 + 256 + h*HD_ + d0);
        #pragma unroll
        for (int e = 0; e < 8; ++e)
            Vt[(d0 + e)*296 + k] = u.s[e];
    }
}

template<int HF>
__device__ inline void pv_half(const unsigned (&pk)[36][2], f32x4 (&cacc)[4],
                               const u16* __restrict__ Vt, int lane) {
    int s1 = (lane & 15) + ((lane & 16) << 1);
    int s2 = s1 + 16;
    bool hi = (lane & 32) != 0;
    #pragma unroll
    for (int t9 = 0; t9 < 9; ++t9) {
        const int t = HF*9 + t9;
        unsigned A01 = __shfl((int)pk[2*t  ][0], s1, 64);
        unsigned A23 = __shfl((int)pk[2*t  ][1], s1, 64);
        unsigned B01 = __shfl((int)pk[2*t+1][0], s1, 64);
        unsigned B23 = __shfl((int)pk[2*t+1][1], s1, 64);
        unsigned C01 = __shfl((int)pk[2*t  ][0], s2, 64);
        unsigned C23 = __shfl((int)pk[2*t  ][1], s2, 64);
        unsigned D01 = __shfl((int)pk[2*t+1][0], s2, 64);
        unsigned D23 = __shfl((int)pk[2*t+1][1], s2, 64);
        union { unsigned w[4]; bf16x8 v; } bu;
        bu.w[0] = hi ? B01 : A01;
        bu.w[1] = hi ? B23 : A23;
        bu.w[2] = hi ? D01 : C01;
        bu.w[3] = hi ? D23 : C23;
        int colb = 32*t - 288*HF + 8*(lane >> 4);
        #pragma unroll
        for (int dt = 0; dt < 4; ++dt) {
            bf16x8 a = *(const bf16x8*)&Vt[(16*dt + (lane & 15))*296 + colb];
            cacc[dt] = __builtin_amdgcn_mfma_f32_16x16x32_bf16(a, bu.v, cacc[dt], 0, 0, 0);
        }
    }
}

__global__ __launch_bounds__(256, 2)
void attn_mfma_kernel(const u16* __restrict__ Qbf, const u16* __restrict__ KV,
                      const float* __restrict__ mask,
                      float* __restrict__ attn_out, u16* __restrict__ ctxb) {
    __shared__ u16 Vt[64*296];
    __shared__ float Msk[576];
    int tid = threadIdx.x;
    int lane = tid & 63, wid = tid >> 6;
    int qb, bh;
    xcd_remap<9, 128>(qb, bh);           // cluster all q-blocks of a (b,h) on one XCD
    int b = bh >> 2, h = bh & 3;
    int q0 = qb * 64;
    int g = lane >> 4;
    int qrow = q0 + wid*16 + (lane & 15);

    if (tid < 144) {
        float4 mv = *(const float4*)(mask + b*N_ + tid*4);
        *(float4*)&Msk[tid*4] = make_float4(ALPHA_*mv.x, ALPHA_*mv.y, ALPHA_*mv.z, ALPHA_*mv.w);
    }
    stage_v_half(KV, Vt, b, h, 0, tid);
    __syncthreads();

    const u16* qp = Qbf + ((size_t)(b*N_) + qrow)*INNER_ + h*HD_ + g*8;
    bf16x8 qf0 = *(const bf16x8*)qp;
    bf16x8 qf1 = *(const bf16x8*)(qp + 32);

    f32x4 acc[36];
    #pragma unroll
    for (int T = 0; T < 36; ++T) acc[T] = (f32x4){0.f, 0.f, 0.f, 0.f};

    const u16* kp = KV + ((size_t)(b*N_) + (lane & 15))*512 + h*HD_ + g*8;
    bf16x8 kb[2][2];
    kb[0][0] = *(const bf16x8*)(kp);
    kb[0][1] = *(const bf16x8*)(kp + 32);
    kb[1][0] = *(const bf16x8*)(kp + 16*512);
    kb[1][1] = *(const bf16x8*)(kp + 16*512 + 32);
    #pragma unroll
    for (int T = 0; T < 36; ++T) {
        bf16x8 n0, n1;
        if (T + 2 < 36) {
            n0 = *(const bf16x8*)(kp + (size_t)(T+2)*16*512);
            n1 = *(const bf16x8*)(kp + (size_t)(T+2)*16*512 + 32);
        }
        acc[T] = __builtin_amdgcn_mfma_f32_16x16x32_bf16(kb[T&1][0], qf0, acc[T], 0, 0, 0);
        acc[T] = __builtin_amdgcn_mfma_f32_16x16x32_bf16(kb[T&1][1], qf1, acc[T], 0, 0, 0);
        if (T + 2 < 36) { kb[T&1][0] = n0; kb[T&1][1] = n1; }
    }

    float m = -1e30f;
    #pragma unroll
    for (int T = 0; T < 36; ++T) {
        float4 mk = *(const float4*)&Msk[16*T + 4*g];
        acc[T][0] = acc[T][0]*0.125f + mk.x;
        acc[T][1] = acc[T][1]*0.125f + mk.y;
        acc[T][2] = acc[T][2]*0.125f + mk.z;
        acc[T][3] = acc[T][3]*0.125f + mk.w;
        m = fmaxf(m, fmaxf(fmaxf(acc[T][0], acc[T][1]), fmaxf(acc[T][2], acc[T][3])));
    }
    m = fmaxf(m, __shfl_xor(m, 16, 64));
    m = fmaxf(m, __shfl_xor(m, 32, 64));

    float l = 0.f;
    #pragma unroll
    for (int T = 0; T < 36; ++T) {
        acc[T][0] = expf(acc[T][0] - m);
        acc[T][1] = expf(acc[T][1] - m);
        acc[T][2] = expf(acc[T][2] - m);
        acc[T][3] = expf(acc[T][3] - m);
        l += acc[T][0] + acc[T][1] + acc[T][2] + acc[T][3];
    }
    l += __shfl_xor(l, 16, 64);
    l += __shfl_xor(l, 32, 64);
    float inv = 1.f / l;

    unsigned pk[36][2];
    float* ap = attn_out + ((size_t)bh*N_ + qrow)*N_;
    #pragma unroll
    for (int T = 0; T < 36; ++T) {
        float e0 = acc[T][0]*inv, e1 = acc[T][1]*inv;
        float e2 = acc[T][2]*inv, e3 = acc[T][3]*inv;
        f32x4 ov = {e0, e1, e2, e3};
        __builtin_nontemporal_store(ov, (f32x4*)(ap + 16*T + 4*g));
        pk[T][0] = pack2bf(e0, e1);
        pk[T][1] = pack2bf(e2, e3);
    }

    f32x4 cacc[4] = {};
    pv_half<0>(pk, cacc, Vt, lane);
    __syncthreads();
    stage_v_half(KV, Vt, b, h, 1, tid);
    __syncthreads();
    pv_half<1>(pk, cacc, Vt, lane);

    u16* cp = ctxb + ((size_t)(b*N_) + qrow)*INNER_ + h*HD_ + 4*g;
    #pragma unroll
    for (int dt = 0; dt < 4; ++dt) {
        ushort4 o;
        o.x = bfbits(cacc[dt][0]);
        o.y = bfbits(cacc[dt][1]);
        o.z = bfbits(cacc[dt][2]);
        o.w = bfbits(cacc[dt][3]);
        *(ushort4*)(cp + 16*dt) = o;
    }
}

// ---------------------------------------------------------------------------
extern "C" void kernel_launch(void* const* d_in, const int* in_sizes, int n_in,
                              void* d_out, int out_size, void* d_ws, size_t ws_size,
                              hipStream_t stream) {
    const float* query   = (const float*)d_in[0];
    const float* support = (const float*)d_in[1];
    const float* mask    = (const float*)d_in[2];
    const float* ln_q_w  = (const float*)d_in[3];
    const float* ln_q_b  = (const float*)d_in[4];
    const float* ln_s_w  = (const float*)d_in[5];
    const float* ln_s_b  = (const float*)d_in[6];
    const float* Wq      = (const float*)d_in[7];
    const float* bq      = (const float*)d_in[8];
    const float* Wk      = (const float*)d_in[9];
    const float* bk      = (const float*)d_in[10];
    const float* Wv      = (const float*)d_in[11];
    const float* bv      = (const float*)d_in[12];
    const float* Wo      = (const float*)d_in[13];
    const float* bo      = (const float*)d_in[14];
    const float* Wg      = (const float*)d_in[15];
    const float* bg      = (const float*)d_in[16];

    float* out      = (float*)d_out;
    float* attn_out = out + (size_t)M_ * C_;

    char* w = (char*)d_ws;
    u16* Aq    = (u16*)w;  w += (size_t)M_*C_*2;
    u16* As_   = (u16*)w;  w += (size_t)M_*C_*2;
    u16* Wq_b  = (u16*)w;  w += (size_t)INNER_*C_*2;
    u16* Wkv_b = (u16*)w;  w += (size_t)2*INNER_*C_*2;
    u16* Wo_b  = (u16*)w;  w += (size_t)C_*INNER_*2;
    u16* Wg_b  = (u16*)w;  w += (size_t)C_*C_*2;
    float* bkv = (float*)w; w += 512*4;
    u16* Qbf   = (u16*)w;  w += (size_t)M_*INNER_*2;
    u16* KVbf  = (u16*)w;  w += (size_t)M_*2*INNER_*2;
    u16* ctxb  = (u16*)w;  w += (size_t)M_*INNER_*2;

    // Fused LN for both tensors (one launch)
    ln_fused2_kernel<<<dim3(M_/4, 2), dim3(256), 0, stream>>>(
        query, support, ln_q_w, ln_q_b, ln_s_w, ln_s_b, Aq, As_);

    // All weight conversions + combined kv bias
    cvt_weights_kernel<<<dim3(1024), dim3(256), 0, stream>>>(
        Wq, Wk, Wv, Wo, Wg, bk, bv, Wq_b, Wkv_b, Wo_b, Wg_b, bkv);

    // Q + KV projections, one launch, row-band clustered
    qkv_gemm_kernel<<<dim3(6, 144), dim3(256), 0, stream>>>(
        Aq, As_, Wq_b, Wkv_b, bq, bkv, Qbf, KVbf);

    // attention
    attn_mfma_kernel<<<dim3(N_/64, B_*H_), dim3(256), 0, stream>>>(
        Qbf, KVbf, mask, attn_out, ctxb);

    // fused gate + output proj + residual (gate A staged from f32 query)
    final_fused_kernel<<<dim3(8, 144), dim3(256), 0, stream>>>(
        query, Wg_b, bg, ctxb, Wo_b, bo, out);
}